// Round 1
// baseline (1095.376 us; speedup 1.0000x reference)
//
#include <hip/hip_runtime.h>
#include <math.h>

#define F_IN   128
#define HIDC   32
#define NHEAD  4
#define CDIM   40
#define NEG_SLOPE 0.2f

__device__ __forceinline__ float leakyf(float x) { return x > 0.f ? x : NEG_SLOPE * x; }

// ---------------- GEMM: Y[n,OUTC] = X[n,K] @ W[K,OUTC], W cached in LDS ----
template<int K, int OUTC>
__global__ __launch_bounds__(256) void gemm_lds(const float* __restrict__ X,
                                                const float* __restrict__ W,
                                                float* __restrict__ Y, int n)
{
    __shared__ float Wl[K * OUTC];
    for (int i = threadIdx.x; i < K * OUTC; i += 256) Wl[i] = W[i];
    __syncthreads();
    int idx = blockIdx.x * 256 + threadIdx.x;
    if (idx >= n * OUTC) return;
    int node = idx / OUTC;
    int c    = idx - node * OUTC;
    const float* xr = X + (size_t)node * K;
    float acc = 0.f;
#pragma unroll 8
    for (int k = 0; k < K; ++k) acc = fmaf(xr[k], Wl[k * OUTC + c], acc);
    Y[idx] = acc;
}

// ---------------- CSR build -------------------------------------------------
__global__ void count_kernel(const int* __restrict__ dst, unsigned* __restrict__ counts, int e)
{
    int i = blockIdx.x * 256 + threadIdx.x;
    if (i < e) atomicAdd(&counts[dst[i]], 1u);
}

__global__ __launch_bounds__(1024) void scan_kernel(const unsigned* __restrict__ counts,
                                                    unsigned* __restrict__ rs,
                                                    unsigned* __restrict__ cursor, int n)
{
    __shared__ unsigned sums[1024];
    int t  = threadIdx.x;
    int ch = (n + 1023) >> 10;
    int lo = t * ch;
    int hi = lo + ch; if (hi > n) hi = n;
    unsigned s = 0;
    for (int i = lo; i < hi; ++i) s += counts[i];
    sums[t] = s;
    __syncthreads();
    for (int off = 1; off < 1024; off <<= 1) {
        unsigned v = (t >= off) ? sums[t - off] : 0u;
        __syncthreads();
        sums[t] += v;
        __syncthreads();
    }
    unsigned base = (t == 0) ? 0u : sums[t - 1];
    for (int i = lo; i < hi; ++i) {
        rs[i] = base; cursor[i] = base; base += counts[i];
    }
    if (t == 1023) rs[n] = sums[1023];
}

__global__ void fill_kernel(const int* __restrict__ src, const int* __restrict__ dst,
                            unsigned* __restrict__ cursor, unsigned* __restrict__ csr_src, int e)
{
    int i = blockIdx.x * 256 + threadIdx.x;
    if (i >= e) return;
    int d = dst[i];
    unsigned pos = atomicAdd(&cursor[d], 1u);
    csr_src[pos] = (unsigned)src[i];
}

__global__ void norm_kernel(const unsigned* __restrict__ rs, float* __restrict__ nrm, int n)
{
    int i = blockIdx.x * 256 + threadIdx.x;
    if (i >= n) return;
    unsigned deg = rs[i + 1] - rs[i] + 1u;   // + self loop
    nrm[i] = rsqrtf((float)deg);
}

// ---------------- attention logits -----------------------------------------
__global__ void logits1_kernel(const float* __restrict__ h1, const float* __restrict__ aw_s,
                               const float* __restrict__ aw_d, float* __restrict__ as1,
                               float* __restrict__ ad1, int n)
{
    __shared__ float sw[128], dw[128];
    if (threadIdx.x < 128) { sw[threadIdx.x] = aw_s[threadIdx.x]; dw[threadIdx.x] = aw_d[threadIdx.x]; }
    __syncthreads();
    int idx = blockIdx.x * 256 + threadIdx.x;
    if (idx >= n * NHEAD) return;
    int node = idx >> 2, h = idx & 3;
    const float* row = h1 + (size_t)node * F_IN + h * HIDC;
    float s = 0.f, d = 0.f;
#pragma unroll
    for (int k = 0; k < HIDC; ++k) {
        float v = row[k];
        s = fmaf(v, sw[h * HIDC + k], s);
        d = fmaf(v, dw[h * HIDC + k], d);
    }
    as1[idx] = s; ad1[idx] = d;
}

__global__ void logits2_kernel(const float* __restrict__ h2, const float* __restrict__ aw_s,
                               const float* __restrict__ aw_d, float* __restrict__ as2,
                               float* __restrict__ ad2, int n)
{
    __shared__ float sw[CDIM], dw[CDIM];
    if (threadIdx.x < CDIM) { sw[threadIdx.x] = aw_s[threadIdx.x]; dw[threadIdx.x] = aw_d[threadIdx.x]; }
    __syncthreads();
    int i = blockIdx.x * 256 + threadIdx.x;
    if (i >= n) return;
    const float* row = h2 + (size_t)i * CDIM;
    float s = 0.f, d = 0.f;
#pragma unroll
    for (int k = 0; k < CDIM; ++k) {
        float v = row[k];
        s = fmaf(v, sw[k], s);
        d = fmaf(v, dw[k], d);
    }
    as2[i] = s; ad2[i] = d;
}

// ---------------- GAT layer 1 aggregation (one wave per node, fused softmax)
__global__ __launch_bounds__(256) void gat_agg1_kernel(
    const float* __restrict__ h1, const float* __restrict__ as1,
    const float* __restrict__ ad1, const unsigned* __restrict__ rs,
    const unsigned* __restrict__ csr_src, const float* __restrict__ b1,
    float* __restrict__ xg, int n)
{
    int wave = (blockIdx.x * 256 + threadIdx.x) >> 6;
    int lane = threadIdx.x & 63;
    if (wave >= n) return;
    int i = wave;
    int h = lane >> 4;                       // channels (2*lane, 2*lane+1) -> head
    float adv    = ad1[i * 4 + h];
    float e_self = leakyf(as1[i * 4 + h] + adv);
    unsigned beg = rs[i], end = rs[i + 1];

    float m = e_self;
    for (unsigned j = beg; j < end; ++j) {
        unsigned s = csr_src[j];
        m = fmaxf(m, leakyf(as1[s * 4 + h] + adv));
    }
    float wself = __expf(e_self - m);
    float ssum  = wself;
    const float2* h1v = (const float2*)h1;
    float2 hv  = h1v[(size_t)i * 64 + lane];
    float2 acc = make_float2(hv.x * wself, hv.y * wself);
    for (unsigned j = beg; j < end; ++j) {
        unsigned s = csr_src[j];
        float e = leakyf(as1[s * 4 + h] + adv);
        float w = __expf(e - m);
        ssum += w;
        float2 v = h1v[(size_t)s * 64 + lane];
        acc.x = fmaf(v.x, w, acc.x);
        acc.y = fmaf(v.y, w, acc.y);
    }
    float inv = 1.f / ssum;
    int c0 = 2 * lane;
    float o0 = acc.x * inv + b1[c0];
    float o1 = acc.y * inv + b1[c0 + 1];
    o0 = o0 > 0.f ? o0 : __expf(o0) - 1.f;   // ELU
    o1 = o1 > 0.f ? o1 : __expf(o1) - 1.f;
    xg[(size_t)i * F_IN + c0]     = o0;
    xg[(size_t)i * F_IN + c0 + 1] = o1;
}

// ---------------- GAT layer 2 aggregation (heads=1, C=40) -------------------
__global__ __launch_bounds__(256) void gat_agg2_kernel(
    const float* __restrict__ h2, const float* __restrict__ as2,
    const float* __restrict__ ad2, const unsigned* __restrict__ rs,
    const unsigned* __restrict__ csr_src, const float* __restrict__ b2,
    float* __restrict__ out, int n)
{
    int wave = (blockIdx.x * 256 + threadIdx.x) >> 6;
    int lane = threadIdx.x & 63;
    if (wave >= n) return;
    int i = wave;
    bool act = lane < CDIM;
    float adv    = ad2[i];
    float e_self = leakyf(as2[i] + adv);
    unsigned beg = rs[i], end = rs[i + 1];

    float m = e_self;
    for (unsigned j = beg; j < end; ++j) {
        unsigned s = csr_src[j];
        m = fmaxf(m, leakyf(as2[s] + adv));
    }
    float wself = __expf(e_self - m);
    float ssum  = wself;
    float acc   = act ? h2[(size_t)i * CDIM + lane] * wself : 0.f;
    for (unsigned j = beg; j < end; ++j) {
        unsigned s = csr_src[j];
        float w = __expf(leakyf(as2[s] + adv) - m);
        ssum += w;
        if (act) acc = fmaf(h2[(size_t)s * CDIM + lane], w, acc);
    }
    if (act) out[(size_t)i * CDIM + lane] = acc / ssum + b2[lane];
}

// ---------------- GCN aggregation ------------------------------------------
template<int C, bool RELU>
__global__ __launch_bounds__(256) void gcn_agg_kernel(
    const float* __restrict__ g, const float* __restrict__ nrm,
    const unsigned* __restrict__ rs, const unsigned* __restrict__ csr_src,
    const float* __restrict__ b, float* __restrict__ out, int n)
{
    int wave = (blockIdx.x * 256 + threadIdx.x) >> 6;
    int lane = threadIdx.x & 63;
    if (wave >= n) return;
    int i = wave;
    bool act = lane < C;
    float ni = nrm[i];
    unsigned beg = rs[i], end = rs[i + 1];
    float acc = act ? g[(size_t)i * C + lane] * ni * ni : 0.f;
    for (unsigned j = beg; j < end; ++j) {
        unsigned s = csr_src[j];
        float coef = nrm[s] * ni;
        if (act) acc = fmaf(g[(size_t)s * C + lane], coef, acc);
    }
    if (act) {
        float o = acc + b[lane];
        if (RELU) o = fmaxf(o, 0.f);
        out[(size_t)i * C + lane] = o;
    }
}

// ---------------- final head: out = [gcn*wc, gat*wt] @ lin_W + lin_b --------
__global__ __launch_bounds__(256) void final_kernel(
    const float* __restrict__ gcn_o, const float* __restrict__ gat_o,
    const float* __restrict__ W, const float* __restrict__ b,
    const float* __restrict__ wc_p, const float* __restrict__ wt_p,
    float* __restrict__ out, int n)
{
    __shared__ float Wl[80 * CDIM];
    __shared__ float bl[CDIM];
    for (int i = threadIdx.x; i < 80 * CDIM; i += 256) Wl[i] = W[i];
    if (threadIdx.x < CDIM) bl[threadIdx.x] = b[threadIdx.x];
    __syncthreads();
    int idx = blockIdx.x * 256 + threadIdx.x;
    if (idx >= n * CDIM) return;
    float wc = *wc_p, wt = *wt_p;
    int node = idx / CDIM;
    int c    = idx - node * CDIM;
    float acc = bl[c];
    const float* gr = gcn_o + (size_t)node * CDIM;
    const float* tr = gat_o + (size_t)node * CDIM;
#pragma unroll
    for (int k = 0; k < CDIM; ++k)      acc = fmaf(gr[k] * wc, Wl[k * CDIM + c], acc);
#pragma unroll
    for (int k = 0; k < CDIM; ++k)      acc = fmaf(tr[k] * wt, Wl[(CDIM + k) * CDIM + c], acc);
    out[idx] = acc;
}

// ---------------- host ------------------------------------------------------
extern "C" void kernel_launch(void* const* d_in, const int* in_sizes, int n_in,
                              void* d_out, int out_size, void* d_ws, size_t ws_size,
                              hipStream_t stream)
{
    const float* x        = (const float*)d_in[0];
    const int*   eidx     = (const int*)d_in[1];
    const float* gat_W1   = (const float*)d_in[2];
    const float* att_s1   = (const float*)d_in[3];
    const float* att_d1   = (const float*)d_in[4];
    const float* gat_b1   = (const float*)d_in[5];
    const float* gat_W2   = (const float*)d_in[6];
    const float* att_s2   = (const float*)d_in[7];
    const float* att_d2   = (const float*)d_in[8];
    const float* gat_b2   = (const float*)d_in[9];
    const float* gcn_W1   = (const float*)d_in[10];
    const float* gcn_b1   = (const float*)d_in[11];
    const float* gcn_W2   = (const float*)d_in[12];
    const float* gcn_b2   = (const float*)d_in[13];
    const float* lin_W    = (const float*)d_in[14];
    const float* lin_b    = (const float*)d_in[15];
    const float* wc_p     = (const float*)d_in[16];
    const float* wt_p     = (const float*)d_in[17];

    const int n = in_sizes[0] / F_IN;      // 50000
    const int e = in_sizes[1] / 2;         // 800000
    const int* src = eidx;
    const int* dst = eidx + e;

    // workspace carve-up
    char* p = (char*)d_ws;
    auto alloc = [&](size_t bytes) -> void* {
        void* r = (void*)p;
        p += (bytes + 255) & ~(size_t)255;
        return r;
    };
    unsigned* counts  = (unsigned*)alloc((size_t)n * 4);
    unsigned* rs      = (unsigned*)alloc((size_t)(n + 1) * 4);
    unsigned* cursor  = (unsigned*)alloc((size_t)n * 4);
    unsigned* csr_src = (unsigned*)alloc((size_t)e * 4);
    float* nrm     = (float*)alloc((size_t)n * 4);
    float* as1     = (float*)alloc((size_t)n * 4 * 4);
    float* ad1     = (float*)alloc((size_t)n * 4 * 4);
    float* as2     = (float*)alloc((size_t)n * 4);
    float* ad2     = (float*)alloc((size_t)n * 4);
    float* gcn_out = (float*)alloc((size_t)n * CDIM * 4);
    float* gat_out = (float*)alloc((size_t)n * CDIM * 4);
    // big region: reused between GCN phase and GAT phase
    float* h1 = (float*)alloc((size_t)n * F_IN * 4);   // GAT h1  | GCN: g1,gacc1,g2
    float* xg = (float*)alloc((size_t)n * F_IN * 4);   // GAT1 out (post-ELU)
    float* h2 = (float*)alloc((size_t)n * CDIM * 4);   // GAT2 pre-agg features
    float* g1    = h1;                  // n*32
    float* gacc1 = h1 + (size_t)n * 32; // n*32
    float* g2    = h1 + (size_t)n * 64; // n*40

    const int EB = (e + 255) / 256;
    const int NB = (n + 255) / 256;
    const int WB = (n + 3) / 4;        // one wave per node, 4 waves/block

    // ---- CSR build ----
    hipMemsetAsync(counts, 0, (size_t)n * 4, stream);
    count_kernel<<<EB, 256, 0, stream>>>(dst, counts, e);
    scan_kernel<<<1, 1024, 0, stream>>>(counts, rs, cursor, n);
    fill_kernel<<<EB, 256, 0, stream>>>(src, dst, cursor, csr_src, e);
    norm_kernel<<<NB, 256, 0, stream>>>(rs, nrm, n);

    // ---- GCN branch ----
    gemm_lds<128, 32><<<(n * 32 + 255) / 256, 256, 0, stream>>>(x, gcn_W1, g1, n);
    gcn_agg_kernel<32, true><<<WB, 256, 0, stream>>>(g1, nrm, rs, csr_src, gcn_b1, gacc1, n);
    gemm_lds<32, 40><<<(n * 40 + 255) / 256, 256, 0, stream>>>(gacc1, gcn_W2, g2, n);
    gcn_agg_kernel<40, false><<<WB, 256, 0, stream>>>(g2, nrm, rs, csr_src, gcn_b2, gcn_out, n);

    // ---- GAT branch ----
    gemm_lds<128, 128><<<(n * 128 + 255) / 256, 256, 0, stream>>>(x, gat_W1, h1, n);
    logits1_kernel<<<(n * 4 + 255) / 256, 256, 0, stream>>>(h1, att_s1, att_d1, as1, ad1, n);
    gat_agg1_kernel<<<WB, 256, 0, stream>>>(h1, as1, ad1, rs, csr_src, gat_b1, xg, n);
    gemm_lds<128, 40><<<(n * 40 + 255) / 256, 256, 0, stream>>>(xg, gat_W2, h2, n);
    logits2_kernel<<<NB, 256, 0, stream>>>(h2, att_s2, att_d2, as2, ad2, n);
    gat_agg2_kernel<<<WB, 256, 0, stream>>>(h2, as2, ad2, rs, csr_src, gat_b2, gat_out, n);

    // ---- head ----
    final_kernel<<<(n * CDIM + 255) / 256, 256, 0, stream>>>(
        gcn_out, gat_out, lin_W, lin_b, wc_p, wt_p, (float*)d_out, n);
}

// Round 2
// 824.495 us; speedup vs baseline: 1.3285x; 1.3285x over previous
//
#include <hip/hip_runtime.h>
#include <math.h>

#define F_IN   128
#define HIDC   32
#define NHEAD  4
#define CDIM   40
#define NEG_SLOPE 0.2f

__device__ __forceinline__ float leakyf(float x) { return x > 0.f ? x : NEG_SLOPE * x; }

// ---------------- tiled GEMM: Y[n,OUTC] = X[n,K] @ W[K,OUTC] (+bias) --------
// Each thread computes 4 nodes x 4 cols. X tile staged transposed in LDS
// (pad +4 floats: keeps 16B alignment of rows, breaks bank conflicts).
template<int K, int OUTC, int BN, int BK>
__global__ __launch_bounds__((OUTC / 4) * (BN / 4)) void gemm_tile(
    const float* __restrict__ X, const float* __restrict__ W,
    const float* __restrict__ bias, float* __restrict__ Y, int n)
{
    constexpr int CG = OUTC / 4;          // col groups
    constexpr int NG = BN / 4;            // node groups
    constexpr int NT = CG * NG;           // threads per block
    __shared__ float Xs[BK][BN + 4];
    __shared__ float Ws[BK][OUTC];
    const int tid = threadIdx.x;
    const int cg = tid % CG, ng = tid / CG;
    const int node0 = blockIdx.x * BN;
    float acc[4][4] = {};

    for (int kb = 0; kb < K; kb += BK) {
        // stage X^T: consecutive threads read consecutive float4 along k (coalesced)
        for (int idx = tid; idx < BN * (BK / 4); idx += NT) {
            int nd = idx / (BK / 4);
            int kq = idx % (BK / 4);
            int gnode = node0 + nd;
            float4 v = (gnode < n) ? *(const float4*)&X[(size_t)gnode * K + kb + kq * 4]
                                   : make_float4(0.f, 0.f, 0.f, 0.f);
            Xs[kq * 4 + 0][nd] = v.x;
            Xs[kq * 4 + 1][nd] = v.y;
            Xs[kq * 4 + 2][nd] = v.z;
            Xs[kq * 4 + 3][nd] = v.w;
        }
        // stage W tile (row-major, coalesced float4)
        for (int idx = tid; idx < BK * CG; idx += NT) {
            int kk = idx / CG;
            int cq = idx % CG;
            *(float4*)&Ws[kk][cq * 4] = *(const float4*)&W[(size_t)(kb + kk) * OUTC + cq * 4];
        }
        __syncthreads();
#pragma unroll
        for (int k = 0; k < BK; ++k) {
            float4 xv = *(const float4*)&Xs[k][ng * 4];
            float4 wv = *(const float4*)&Ws[k][cg * 4];
            float xa[4] = {xv.x, xv.y, xv.z, xv.w};
            float wa[4] = {wv.x, wv.y, wv.z, wv.w};
#pragma unroll
            for (int j = 0; j < 4; ++j)
#pragma unroll
                for (int c = 0; c < 4; ++c)
                    acc[j][c] = fmaf(xa[j], wa[c], acc[j][c]);
        }
        __syncthreads();
    }

    float4 bv = make_float4(0.f, 0.f, 0.f, 0.f);
    if (bias) bv = *(const float4*)&bias[cg * 4];
#pragma unroll
    for (int j = 0; j < 4; ++j) {
        int gnode = node0 + ng * 4 + j;
        if (gnode < n) {
            float4 o = make_float4(acc[j][0] + bv.x, acc[j][1] + bv.y,
                                   acc[j][2] + bv.z, acc[j][3] + bv.w);
            *(float4*)&Y[(size_t)gnode * OUTC + cg * 4] = o;
        }
    }
}

// ---------------- CSR build -------------------------------------------------
__global__ void count_kernel(const int* __restrict__ dst, unsigned* __restrict__ counts, int e)
{
    int i = blockIdx.x * 256 + threadIdx.x;
    if (i < e) atomicAdd(&counts[dst[i]], 1u);
}

__global__ __launch_bounds__(1024) void scan_kernel(const unsigned* __restrict__ counts,
                                                    unsigned* __restrict__ rs,
                                                    unsigned* __restrict__ cursor, int n)
{
    __shared__ unsigned sums[1024];
    int t  = threadIdx.x;
    int ch = (n + 1023) >> 10;
    int lo = t * ch;
    int hi = lo + ch; if (hi > n) hi = n;
    unsigned s = 0;
    for (int i = lo; i < hi; ++i) s += counts[i];
    sums[t] = s;
    __syncthreads();
    for (int off = 1; off < 1024; off <<= 1) {
        unsigned v = (t >= off) ? sums[t - off] : 0u;
        __syncthreads();
        sums[t] += v;
        __syncthreads();
    }
    unsigned base = (t == 0) ? 0u : sums[t - 1];
    for (int i = lo; i < hi; ++i) {
        rs[i] = base; cursor[i] = base; base += counts[i];
    }
    if (t == 1023) rs[n] = sums[1023];
}

__global__ void fill_kernel(const int* __restrict__ src, const int* __restrict__ dst,
                            unsigned* __restrict__ cursor, unsigned* __restrict__ csr_src, int e)
{
    int i = blockIdx.x * 256 + threadIdx.x;
    if (i >= e) return;
    int d = dst[i];
    unsigned pos = atomicAdd(&cursor[d], 1u);
    csr_src[pos] = (unsigned)src[i];
}

__global__ void norm_kernel(const unsigned* __restrict__ rs, float* __restrict__ nrm, int n)
{
    int i = blockIdx.x * 256 + threadIdx.x;
    if (i >= n) return;
    unsigned deg = rs[i + 1] - rs[i] + 1u;   // + self loop
    nrm[i] = rsqrtf((float)deg);
}

// ---------------- attention logits -----------------------------------------
__global__ void logits1_kernel(const float* __restrict__ h1, const float* __restrict__ aw_s,
                               const float* __restrict__ aw_d, float* __restrict__ as1,
                               float* __restrict__ ad1, int n)
{
    __shared__ float sw[128], dw[128];
    if (threadIdx.x < 128) { sw[threadIdx.x] = aw_s[threadIdx.x]; dw[threadIdx.x] = aw_d[threadIdx.x]; }
    __syncthreads();
    int idx = blockIdx.x * 256 + threadIdx.x;
    if (idx >= n * NHEAD) return;
    int node = idx >> 2, h = idx & 3;
    const float* row = h1 + (size_t)node * F_IN + h * HIDC;
    float s = 0.f, d = 0.f;
#pragma unroll
    for (int k = 0; k < HIDC; ++k) {
        float v = row[k];
        s = fmaf(v, sw[h * HIDC + k], s);
        d = fmaf(v, dw[h * HIDC + k], d);
    }
    as1[idx] = s; ad1[idx] = d;
}

__global__ void logits2_kernel(const float* __restrict__ h2, const float* __restrict__ aw_s,
                               const float* __restrict__ aw_d, float* __restrict__ as2,
                               float* __restrict__ ad2, int n)
{
    __shared__ float sw[CDIM], dw[CDIM];
    if (threadIdx.x < CDIM) { sw[threadIdx.x] = aw_s[threadIdx.x]; dw[threadIdx.x] = aw_d[threadIdx.x]; }
    __syncthreads();
    int i = blockIdx.x * 256 + threadIdx.x;
    if (i >= n) return;
    const float* row = h2 + (size_t)i * CDIM;
    float s = 0.f, d = 0.f;
#pragma unroll
    for (int k = 0; k < CDIM; ++k) {
        float v = row[k];
        s = fmaf(v, sw[k], s);
        d = fmaf(v, dw[k], d);
    }
    as2[i] = s; ad2[i] = d;
}

// ---------------- GAT layer 1 aggregation (one wave per node, fused softmax)
__global__ __launch_bounds__(256) void gat_agg1_kernel(
    const float* __restrict__ h1, const float* __restrict__ as1,
    const float* __restrict__ ad1, const unsigned* __restrict__ rs,
    const unsigned* __restrict__ csr_src, const float* __restrict__ b1,
    float* __restrict__ xg, int n)
{
    int wave = (blockIdx.x * 256 + threadIdx.x) >> 6;
    int lane = threadIdx.x & 63;
    if (wave >= n) return;
    int i = wave;
    int h = lane >> 4;                       // channels (2*lane, 2*lane+1) -> head
    float adv    = ad1[i * 4 + h];
    float e_self = leakyf(as1[i * 4 + h] + adv);
    unsigned beg = rs[i], end = rs[i + 1];

    float m = e_self;
    for (unsigned j = beg; j < end; ++j) {
        unsigned s = csr_src[j];
        m = fmaxf(m, leakyf(as1[s * 4 + h] + adv));
    }
    float wself = __expf(e_self - m);
    float ssum  = wself;
    const float2* h1v = (const float2*)h1;
    float2 hv  = h1v[(size_t)i * 64 + lane];
    float2 acc = make_float2(hv.x * wself, hv.y * wself);
    for (unsigned j = beg; j < end; ++j) {
        unsigned s = csr_src[j];
        float e = leakyf(as1[s * 4 + h] + adv);
        float w = __expf(e - m);
        ssum += w;
        float2 v = h1v[(size_t)s * 64 + lane];
        acc.x = fmaf(v.x, w, acc.x);
        acc.y = fmaf(v.y, w, acc.y);
    }
    float inv = 1.f / ssum;
    int c0 = 2 * lane;
    float o0 = acc.x * inv + b1[c0];
    float o1 = acc.y * inv + b1[c0 + 1];
    o0 = o0 > 0.f ? o0 : __expf(o0) - 1.f;   // ELU
    o1 = o1 > 0.f ? o1 : __expf(o1) - 1.f;
    xg[(size_t)i * F_IN + c0]     = o0;
    xg[(size_t)i * F_IN + c0 + 1] = o1;
}

// ---------------- GAT layer 2 aggregation (heads=1, C=40) -------------------
// Writes (acc/ssum + b2[c]) * (*scale_p) into out[i*ostride + c].
__global__ __launch_bounds__(256) void gat_agg2_kernel(
    const float* __restrict__ h2, const float* __restrict__ as2,
    const float* __restrict__ ad2, const unsigned* __restrict__ rs,
    const unsigned* __restrict__ csr_src, const float* __restrict__ b2,
    const float* __restrict__ scale_p, float* __restrict__ out, int ostride, int n)
{
    int wave = (blockIdx.x * 256 + threadIdx.x) >> 6;
    int lane = threadIdx.x & 63;
    if (wave >= n) return;
    int i = wave;
    bool act = lane < CDIM;
    float adv    = ad2[i];
    float e_self = leakyf(as2[i] + adv);
    unsigned beg = rs[i], end = rs[i + 1];

    float m = e_self;
    for (unsigned j = beg; j < end; ++j) {
        unsigned s = csr_src[j];
        m = fmaxf(m, leakyf(as2[s] + adv));
    }
    float wself = __expf(e_self - m);
    float ssum  = wself;
    float acc   = act ? h2[(size_t)i * CDIM + lane] * wself : 0.f;
    for (unsigned j = beg; j < end; ++j) {
        unsigned s = csr_src[j];
        float w = __expf(leakyf(as2[s] + adv) - m);
        ssum += w;
        if (act) acc = fmaf(h2[(size_t)s * CDIM + lane], w, acc);
    }
    if (act) out[(size_t)i * ostride + lane] = (acc / ssum + b2[lane]) * (*scale_p);
}

// ---------------- GCN aggregation ------------------------------------------
// out[i*ostride + c] = act( (sum + b[c]) ) * scale (scale==nullptr -> 1)
template<int C, bool RELU>
__global__ __launch_bounds__(256) void gcn_agg_kernel(
    const float* __restrict__ g, const float* __restrict__ nrm,
    const unsigned* __restrict__ rs, const unsigned* __restrict__ csr_src,
    const float* __restrict__ b, const float* __restrict__ scale_p,
    float* __restrict__ out, int ostride, int n)
{
    int wave = (blockIdx.x * 256 + threadIdx.x) >> 6;
    int lane = threadIdx.x & 63;
    if (wave >= n) return;
    int i = wave;
    bool act = lane < C;
    float ni = nrm[i];
    unsigned beg = rs[i], end = rs[i + 1];
    float acc = act ? g[(size_t)i * C + lane] * ni * ni : 0.f;
    for (unsigned j = beg; j < end; ++j) {
        unsigned s = csr_src[j];
        float coef = nrm[s] * ni;
        if (act) acc = fmaf(g[(size_t)s * C + lane], coef, acc);
    }
    if (act) {
        float o = acc + b[lane];
        if (RELU) o = fmaxf(o, 0.f);
        if (scale_p) o *= *scale_p;
        out[(size_t)i * ostride + lane] = o;
    }
}

// ---------------- host ------------------------------------------------------
extern "C" void kernel_launch(void* const* d_in, const int* in_sizes, int n_in,
                              void* d_out, int out_size, void* d_ws, size_t ws_size,
                              hipStream_t stream)
{
    const float* x        = (const float*)d_in[0];
    const int*   eidx     = (const int*)d_in[1];
    const float* gat_W1   = (const float*)d_in[2];
    const float* att_s1   = (const float*)d_in[3];
    const float* att_d1   = (const float*)d_in[4];
    const float* gat_b1   = (const float*)d_in[5];
    const float* gat_W2   = (const float*)d_in[6];
    const float* att_s2   = (const float*)d_in[7];
    const float* att_d2   = (const float*)d_in[8];
    const float* gat_b2   = (const float*)d_in[9];
    const float* gcn_W1   = (const float*)d_in[10];
    const float* gcn_b1   = (const float*)d_in[11];
    const float* gcn_W2   = (const float*)d_in[12];
    const float* gcn_b2   = (const float*)d_in[13];
    const float* lin_W    = (const float*)d_in[14];
    const float* lin_b    = (const float*)d_in[15];
    const float* wc_p     = (const float*)d_in[16];
    const float* wt_p     = (const float*)d_in[17];

    const int n = in_sizes[0] / F_IN;      // 50000
    const int e = in_sizes[1] / 2;         // 800000
    const int* src = eidx;
    const int* dst = eidx + e;

    // workspace carve-up
    char* p = (char*)d_ws;
    auto alloc = [&](size_t bytes) -> void* {
        void* r = (void*)p;
        p += (bytes + 255) & ~(size_t)255;
        return r;
    };
    unsigned* counts  = (unsigned*)alloc((size_t)n * 4);
    unsigned* rs      = (unsigned*)alloc((size_t)(n + 1) * 4);
    unsigned* cursor  = (unsigned*)alloc((size_t)n * 4);
    unsigned* csr_src = (unsigned*)alloc((size_t)e * 4);
    float* nrm     = (float*)alloc((size_t)n * 4);
    float* as1     = (float*)alloc((size_t)n * 4 * 4);
    float* ad1     = (float*)alloc((size_t)n * 4 * 4);
    float* as2     = (float*)alloc((size_t)n * 4);
    float* ad2     = (float*)alloc((size_t)n * 4);
    float* cat     = (float*)alloc((size_t)n * 80 * 4);   // [gcn*wc | gat*wt]
    // big region: reused between GCN phase and GAT phase
    float* h1 = (float*)alloc((size_t)n * F_IN * 4);   // GAT h1  | GCN: g1,gacc1,g2
    float* xg = (float*)alloc((size_t)n * F_IN * 4);   // GAT1 out (post-ELU)
    float* h2 = (float*)alloc((size_t)n * CDIM * 4);   // GAT2 pre-agg features
    float* g1    = h1;                  // n*32
    float* gacc1 = h1 + (size_t)n * 32; // n*32
    float* g2    = h1 + (size_t)n * 64; // n*40

    const int EB = (e + 255) / 256;
    const int NB = (n + 255) / 256;
    const int WB = (n + 3) / 4;        // one wave per node, 4 waves/block

    // ---- CSR build ----
    hipMemsetAsync(counts, 0, (size_t)n * 4, stream);
    count_kernel<<<EB, 256, 0, stream>>>(dst, counts, e);
    scan_kernel<<<1, 1024, 0, stream>>>(counts, rs, cursor, n);
    fill_kernel<<<EB, 256, 0, stream>>>(src, dst, cursor, csr_src, e);
    norm_kernel<<<NB, 256, 0, stream>>>(rs, nrm, n);

    // ---- GCN branch ----
    gemm_tile<128, 32, 128, 32><<<(n + 127) / 128, 256, 0, stream>>>(x, gcn_W1, nullptr, g1, n);
    gcn_agg_kernel<32, true><<<WB, 256, 0, stream>>>(g1, nrm, rs, csr_src, gcn_b1, nullptr, gacc1, 32, n);
    gemm_tile<32, 40, 128, 32><<<(n + 127) / 128, 320, 0, stream>>>(gacc1, gcn_W2, nullptr, g2, n);
    gcn_agg_kernel<40, false><<<WB, 256, 0, stream>>>(g2, nrm, rs, csr_src, gcn_b2, wc_p, cat, 80, n);

    // ---- GAT branch ----
    gemm_tile<128, 128, 64, 32><<<(n + 63) / 64, 512, 0, stream>>>(x, gat_W1, nullptr, h1, n);
    logits1_kernel<<<(n * 4 + 255) / 256, 256, 0, stream>>>(h1, att_s1, att_d1, as1, ad1, n);
    gat_agg1_kernel<<<WB, 256, 0, stream>>>(h1, as1, ad1, rs, csr_src, gat_b1, xg, n);
    gemm_tile<128, 40, 128, 32><<<(n + 127) / 128, 320, 0, stream>>>(xg, gat_W2, nullptr, h2, n);
    logits2_kernel<<<NB, 256, 0, stream>>>(h2, att_s2, att_d2, as2, ad2, n);
    gat_agg2_kernel<<<WB, 256, 0, stream>>>(h2, as2, ad2, rs, csr_src, gat_b2, wt_p, cat + 40, 80, n);

    // ---- head: out = cat @ lin_W + lin_b ----
    gemm_tile<80, 40, 128, 40><<<(n + 127) / 128, 320, 0, stream>>>(cat, lin_W, lin_b, (float*)d_out, n);
}

// Round 3
// 550.271 us; speedup vs baseline: 1.9906x; 1.4983x over previous
//
#include <hip/hip_runtime.h>
#include <math.h>

#define F_IN   128
#define HIDC   32
#define NHEAD  4
#define CDIM   40
#define NEG_SLOPE 0.2f

__device__ __forceinline__ float leakyf(float x) { return x > 0.f ? x : NEG_SLOPE * x; }

__device__ __forceinline__ float wred_max(float v) {
#pragma unroll
    for (int o = 32; o > 0; o >>= 1) v = fmaxf(v, __shfl_xor(v, o, 64));
    return v;
}
__device__ __forceinline__ float wred_sum(float v) {
#pragma unroll
    for (int o = 32; o > 0; o >>= 1) v += __shfl_xor(v, o, 64);
    return v;
}
__device__ __forceinline__ float sel4(float4 v, int h) {
    return (h == 0) ? v.x : (h == 1) ? v.y : (h == 2) ? v.z : v.w;
}

// ---------------- tiled GEMM: Y[n,OUTC] = X[n,K] @ W[K,OUTC] (+bias) --------
// Each thread computes 4 nodes x 4 cols. OSTRIDE lets us write into an
// interleaved [gat|gcn] buffer.
template<int K, int OUTC, int BN, int BK, int OSTRIDE = OUTC>
__global__ __launch_bounds__((OUTC / 4) * (BN / 4)) void gemm_tile(
    const float* __restrict__ X, const float* __restrict__ W,
    const float* __restrict__ bias, float* __restrict__ Y, int n)
{
    constexpr int CG = OUTC / 4;
    constexpr int NG = BN / 4;
    constexpr int NT = CG * NG;
    __shared__ float Xs[BK][BN + 4];
    __shared__ float Ws[BK][OUTC];
    const int tid = threadIdx.x;
    const int cg = tid % CG, ng = tid / CG;
    const int node0 = blockIdx.x * BN;
    float acc[4][4] = {};

    for (int kb = 0; kb < K; kb += BK) {
        for (int idx = tid; idx < BN * (BK / 4); idx += NT) {
            int nd = idx / (BK / 4);
            int kq = idx % (BK / 4);
            int gnode = node0 + nd;
            float4 v = (gnode < n) ? *(const float4*)&X[(size_t)gnode * K + kb + kq * 4]
                                   : make_float4(0.f, 0.f, 0.f, 0.f);
            Xs[kq * 4 + 0][nd] = v.x;
            Xs[kq * 4 + 1][nd] = v.y;
            Xs[kq * 4 + 2][nd] = v.z;
            Xs[kq * 4 + 3][nd] = v.w;
        }
        for (int idx = tid; idx < BK * CG; idx += NT) {
            int kk = idx / CG;
            int cq = idx % CG;
            *(float4*)&Ws[kk][cq * 4] = *(const float4*)&W[(size_t)(kb + kk) * OUTC + cq * 4];
        }
        __syncthreads();
#pragma unroll
        for (int k = 0; k < BK; ++k) {
            float4 xv = *(const float4*)&Xs[k][ng * 4];
            float4 wv = *(const float4*)&Ws[k][cg * 4];
            float xa[4] = {xv.x, xv.y, xv.z, xv.w};
            float wa[4] = {wv.x, wv.y, wv.z, wv.w};
#pragma unroll
            for (int j = 0; j < 4; ++j)
#pragma unroll
                for (int c = 0; c < 4; ++c)
                    acc[j][c] = fmaf(xa[j], wa[c], acc[j][c]);
        }
        __syncthreads();
    }

    float4 bv = make_float4(0.f, 0.f, 0.f, 0.f);
    if (bias) bv = *(const float4*)&bias[cg * 4];
#pragma unroll
    for (int j = 0; j < 4; ++j) {
        int gnode = node0 + ng * 4 + j;
        if (gnode < n) {
            float4 o = make_float4(acc[j][0] + bv.x, acc[j][1] + bv.y,
                                   acc[j][2] + bv.z, acc[j][3] + bv.w);
            *(float4*)&Y[(size_t)gnode * OSTRIDE + cg * 4] = o;
        }
    }
}

// ---------------- CSR build -------------------------------------------------
__global__ void count_kernel(const int* __restrict__ dst, unsigned* __restrict__ counts, int e)
{
    int i = blockIdx.x * 256 + threadIdx.x;
    if (i < e) atomicAdd(&counts[dst[i]], 1u);
}

__global__ __launch_bounds__(1024) void scan_kernel(const unsigned* __restrict__ counts,
                                                    unsigned* __restrict__ rs,
                                                    unsigned* __restrict__ cursor, int n)
{
    __shared__ unsigned sums[1024];
    int t  = threadIdx.x;
    int ch = (n + 1023) >> 10;
    int lo = t * ch;
    int hi = lo + ch; if (hi > n) hi = n;
    unsigned s = 0;
    for (int i = lo; i < hi; ++i) s += counts[i];
    sums[t] = s;
    __syncthreads();
    for (int off = 1; off < 1024; off <<= 1) {
        unsigned v = (t >= off) ? sums[t - off] : 0u;
        __syncthreads();
        sums[t] += v;
        __syncthreads();
    }
    unsigned base = (t == 0) ? 0u : sums[t - 1];
    for (int i = lo; i < hi; ++i) {
        rs[i] = base; cursor[i] = base; base += counts[i];
    }
    if (t == 1023) rs[n] = sums[1023];
}

__global__ void fill_kernel(const int* __restrict__ src, const int* __restrict__ dst,
                            unsigned* __restrict__ cursor, unsigned* __restrict__ csr_src, int e)
{
    int i = blockIdx.x * 256 + threadIdx.x;
    if (i >= e) return;
    int d = dst[i];
    unsigned pos = atomicAdd(&cursor[d], 1u);
    csr_src[pos] = (unsigned)src[i];
}

__global__ void norm_kernel(const unsigned* __restrict__ rs, float* __restrict__ nrm, int n)
{
    int i = blockIdx.x * 256 + threadIdx.x;
    if (i >= n) return;
    unsigned deg = rs[i + 1] - rs[i] + 1u;   // + self loop
    nrm[i] = rsqrtf((float)deg);
}

// ---------------- attention logits -----------------------------------------
__global__ void logits1_kernel(const float* __restrict__ h1, const float* __restrict__ aw_s,
                               const float* __restrict__ aw_d, float* __restrict__ as1,
                               float* __restrict__ ad1, int n)
{
    __shared__ float sw[128], dw[128];
    if (threadIdx.x < 128) { sw[threadIdx.x] = aw_s[threadIdx.x]; dw[threadIdx.x] = aw_d[threadIdx.x]; }
    __syncthreads();
    int idx = blockIdx.x * 256 + threadIdx.x;
    if (idx >= n * NHEAD) return;
    int node = idx >> 2, h = idx & 3;
    const float* row = h1 + (size_t)node * F_IN + h * HIDC;
    float s = 0.f, d = 0.f;
#pragma unroll
    for (int k = 0; k < HIDC; ++k) {
        float v = row[k];
        s = fmaf(v, sw[h * HIDC + k], s);
        d = fmaf(v, dw[h * HIDC + k], d);
    }
    as1[idx] = s; ad1[idx] = d;
}

// h2 lives in the interleaved hg buffer: row stride 80, gat half at offset 0
__global__ void logits2_kernel(const float* __restrict__ hg, const float* __restrict__ aw_s,
                               const float* __restrict__ aw_d, float* __restrict__ as2,
                               float* __restrict__ ad2, int n)
{
    __shared__ float sw[CDIM], dw[CDIM];
    if (threadIdx.x < CDIM) { sw[threadIdx.x] = aw_s[threadIdx.x]; dw[threadIdx.x] = aw_d[threadIdx.x]; }
    __syncthreads();
    int i = blockIdx.x * 256 + threadIdx.x;
    if (i >= n) return;
    const float* row = hg + (size_t)i * 80;
    float s = 0.f, d = 0.f;
#pragma unroll
    for (int k = 0; k < CDIM; ++k) {
        float v = row[k];
        s = fmaf(v, sw[k], s);
        d = fmaf(v, dw[k], d);
    }
    as2[i] = s; ad2[i] = d;
}

// ---------------- GAT layer 1 aggregation ----------------------------------
// Phase A: lane-parallel logit passes (max, then w=exp(e-m)), cached in LDS.
// Phase B: channel-parallel gather, unrolled x4 for MLP.
#define CAP1 96
__global__ __launch_bounds__(256) void gat_agg1_kernel(
    const float* __restrict__ h1, const float* __restrict__ as1,
    const float* __restrict__ ad1, const unsigned* __restrict__ rs,
    const unsigned* __restrict__ csr_src, const float* __restrict__ b1,
    float* __restrict__ xg, int n)
{
    __shared__ unsigned sidx[4][CAP1];
    __shared__ float    w4[4][CAP1][4];
    const int wid = threadIdx.x >> 6;
    const int lane = threadIdx.x & 63;
    const int i = blockIdx.x * 4 + wid;
    if (i >= n) return;
    const unsigned beg = rs[i];
    const int deg = (int)(rs[i + 1] - beg);
    const float4* as1v = (const float4*)as1;
    float4 av = as1v[i];
    float4 dv = ((const float4*)ad1)[i];
    float4 es = make_float4(leakyf(av.x + dv.x), leakyf(av.y + dv.y),
                            leakyf(av.z + dv.z), leakyf(av.w + dv.w));
    float m0 = es.x, m1 = es.y, m2 = es.z, m3 = es.w;
    for (int k = lane; k < deg; k += 64) {
        unsigned s = csr_src[beg + k];
        float4 a = as1v[s];
        float e0 = leakyf(a.x + dv.x), e1 = leakyf(a.y + dv.y);
        float e2 = leakyf(a.z + dv.z), e3 = leakyf(a.w + dv.w);
        if (k < CAP1) {
            sidx[wid][k] = s;
            w4[wid][k][0] = e0; w4[wid][k][1] = e1;
            w4[wid][k][2] = e2; w4[wid][k][3] = e3;
        }
        m0 = fmaxf(m0, e0); m1 = fmaxf(m1, e1);
        m2 = fmaxf(m2, e2); m3 = fmaxf(m3, e3);
    }
    m0 = wred_max(m0); m1 = wred_max(m1); m2 = wred_max(m2); m3 = wred_max(m3);
    float s0 = 0.f, s1 = 0.f, s2 = 0.f, s3 = 0.f;
    if (lane == 0) {
        s0 = __expf(es.x - m0); s1 = __expf(es.y - m1);
        s2 = __expf(es.z - m2); s3 = __expf(es.w - m3);
    }
    const int dc = deg < CAP1 ? deg : CAP1;
    for (int k = lane; k < dc; k += 64) {
        float w0 = __expf(w4[wid][k][0] - m0); w4[wid][k][0] = w0; s0 += w0;
        float w1 = __expf(w4[wid][k][1] - m1); w4[wid][k][1] = w1; s1 += w1;
        float w2 = __expf(w4[wid][k][2] - m2); w4[wid][k][2] = w2; s2 += w2;
        float w3 = __expf(w4[wid][k][3] - m3); w4[wid][k][3] = w3; s3 += w3;
    }
    for (int k = CAP1 + lane; k < deg; k += 64) {
        unsigned s = csr_src[beg + k];
        float4 a = as1v[s];
        s0 += __expf(leakyf(a.x + dv.x) - m0);
        s1 += __expf(leakyf(a.y + dv.y) - m1);
        s2 += __expf(leakyf(a.z + dv.z) - m2);
        s3 += __expf(leakyf(a.w + dv.w) - m3);
    }
    s0 = wred_sum(s0); s1 = wred_sum(s1); s2 = wred_sum(s2); s3 = wred_sum(s3);
    __threadfence_block();
    // phase B: lane -> channels (2*lane, 2*lane+1), head = lane>>4
    const int h = lane >> 4;
    const float mh   = sel4(make_float4(m0, m1, m2, m3), h);
    const float advh = sel4(dv, h);
    const float ssh  = sel4(make_float4(s0, s1, s2, s3), h);
    const float wself = __expf(sel4(es, h) - mh);
    const float2* h1v = (const float2*)h1;
    float2 hv = h1v[(size_t)i * 64 + lane];
    float2 acc = make_float2(hv.x * wself, hv.y * wself);
    auto edge = [&](int j, unsigned& s, float& w) {
        if (j < CAP1) { s = sidx[wid][j]; w = w4[wid][j][h]; }
        else {
            s = csr_src[beg + j];
            float4 a = as1v[s];
            w = __expf(leakyf(sel4(a, h) + advh) - mh);
        }
    };
    int j = 0;
    for (; j + 4 <= deg; j += 4) {
        unsigned sa, sb, sc, sd; float wa, wb, wc, wd;
        edge(j, sa, wa); edge(j + 1, sb, wb); edge(j + 2, sc, wc); edge(j + 3, sd, wd);
        float2 va = h1v[(size_t)sa * 64 + lane];
        float2 vb = h1v[(size_t)sb * 64 + lane];
        float2 vc = h1v[(size_t)sc * 64 + lane];
        float2 vd = h1v[(size_t)sd * 64 + lane];
        acc.x = fmaf(va.x, wa, acc.x); acc.y = fmaf(va.y, wa, acc.y);
        acc.x = fmaf(vb.x, wb, acc.x); acc.y = fmaf(vb.y, wb, acc.y);
        acc.x = fmaf(vc.x, wc, acc.x); acc.y = fmaf(vc.y, wc, acc.y);
        acc.x = fmaf(vd.x, wd, acc.x); acc.y = fmaf(vd.y, wd, acc.y);
    }
    for (; j < deg; ++j) {
        unsigned s; float w; edge(j, s, w);
        float2 v = h1v[(size_t)s * 64 + lane];
        acc.x = fmaf(v.x, w, acc.x); acc.y = fmaf(v.y, w, acc.y);
    }
    float inv = 1.f / ssh;
    int c0 = 2 * lane;
    float o0 = acc.x * inv + b1[c0];
    float o1 = acc.y * inv + b1[c0 + 1];
    o0 = o0 > 0.f ? o0 : __expf(o0) - 1.f;   // ELU
    o1 = o1 > 0.f ? o1 : __expf(o1) - 1.f;
    xg[(size_t)i * F_IN + c0]     = o0;
    xg[(size_t)i * F_IN + c0 + 1] = o1;
}

// ---------------- fused layer-2 aggregation (GAT heads=1 + GCN), writes cat -
// hg: [n, 80] rows = [gat h2 (40) | gcn g2 (40)]. Lanes 0-19: gat float2,
// lanes 20-39: gcn float2. cat rows = [gcn*wc (40) | gat*wt (40)].
#define CAP2 128
__global__ __launch_bounds__(256) void agg2_fused_kernel(
    const float* __restrict__ hg, const float* __restrict__ as2,
    const float* __restrict__ ad2, const float* __restrict__ nrm,
    const unsigned* __restrict__ rs, const unsigned* __restrict__ csr_src,
    const float* __restrict__ gat_b2, const float* __restrict__ gcn_b2,
    const float* __restrict__ wc_p, const float* __restrict__ wt_p,
    float* __restrict__ cat, int n)
{
    __shared__ unsigned sidx[4][CAP2];
    __shared__ float    wgt[4][CAP2];
    __shared__ float    cf [4][CAP2];
    const int wid = threadIdx.x >> 6;
    const int lane = threadIdx.x & 63;
    const int i = blockIdx.x * 4 + wid;
    if (i >= n) return;
    const unsigned beg = rs[i];
    const int deg = (int)(rs[i + 1] - beg);
    const float adv = ad2[i];
    const float e_self = leakyf(as2[i] + adv);
    const float ni = nrm[i];
    float m = e_self;
    for (int k = lane; k < deg; k += 64) {
        unsigned s = csr_src[beg + k];
        float e = leakyf(as2[s] + adv);
        if (k < CAP2) { sidx[wid][k] = s; wgt[wid][k] = e; cf[wid][k] = nrm[s]; }
        m = fmaxf(m, e);
    }
    m = wred_max(m);
    float ssum = (lane == 0) ? __expf(e_self - m) : 0.f;
    const int dc = deg < CAP2 ? deg : CAP2;
    for (int k = lane; k < dc; k += 64) {
        float w = __expf(wgt[wid][k] - m);
        wgt[wid][k] = w; ssum += w;
    }
    for (int k = CAP2 + lane; k < deg; k += 64) {
        unsigned s = csr_src[beg + k];
        ssum += __expf(leakyf(as2[s] + adv) - m);
    }
    ssum = wred_sum(ssum);
    __threadfence_block();
    const bool act   = lane < 40;
    const bool isgat = lane < 20;
    const float selfw = isgat ? __expf(e_self - m) : ni * ni;
    const float2* rows = (const float2*)hg;
    float2 acc = make_float2(0.f, 0.f);
    if (act) {
        float2 v = rows[(size_t)i * 40 + lane];
        acc.x = v.x * selfw; acc.y = v.y * selfw;
    }
    auto edge = [&](int j, unsigned& s, float& w) {
        if (j < CAP2) {
            s = sidx[wid][j];
            w = isgat ? wgt[wid][j] : cf[wid][j] * ni;
        } else {
            s = csr_src[beg + j];
            w = isgat ? __expf(leakyf(as2[s] + adv) - m) : nrm[s] * ni;
        }
    };
    int j = 0;
    for (; j + 4 <= deg; j += 4) {
        unsigned sa, sb, sc, sd; float wa, wb, wc, wd;
        edge(j, sa, wa); edge(j + 1, sb, wb); edge(j + 2, sc, wc); edge(j + 3, sd, wd);
        if (act) {
            float2 va = rows[(size_t)sa * 40 + lane];
            float2 vb = rows[(size_t)sb * 40 + lane];
            float2 vc = rows[(size_t)sc * 40 + lane];
            float2 vd = rows[(size_t)sd * 40 + lane];
            acc.x = fmaf(va.x, wa, acc.x); acc.y = fmaf(va.y, wa, acc.y);
            acc.x = fmaf(vb.x, wb, acc.x); acc.y = fmaf(vb.y, wb, acc.y);
            acc.x = fmaf(vc.x, wc, acc.x); acc.y = fmaf(vc.y, wc, acc.y);
            acc.x = fmaf(vd.x, wd, acc.x); acc.y = fmaf(vd.y, wd, acc.y);
        }
    }
    for (; j < deg; ++j) {
        unsigned s; float w; edge(j, s, w);
        if (act) {
            float2 v = rows[(size_t)s * 40 + lane];
            acc.x = fmaf(v.x, w, acc.x); acc.y = fmaf(v.y, w, acc.y);
        }
    }
    if (act) {
        if (isgat) {
            float inv = 1.f / ssum, wt = *wt_p;
            int c0 = 2 * lane;
            cat[(size_t)i * 80 + 40 + c0]     = (acc.x * inv + gat_b2[c0]) * wt;
            cat[(size_t)i * 80 + 40 + c0 + 1] = (acc.y * inv + gat_b2[c0 + 1]) * wt;
        } else {
            float wc = *wc_p;
            int c0 = 2 * (lane - 20);
            cat[(size_t)i * 80 + c0]     = (acc.x + gcn_b2[c0]) * wc;
            cat[(size_t)i * 80 + c0 + 1] = (acc.y + gcn_b2[c0 + 1]) * wc;
        }
    }
}

// ---------------- GCN layer-1 aggregation (32 ch, two edges per iteration) --
#define CAPG 128
__global__ __launch_bounds__(256) void gcn_agg1_kernel(
    const float* __restrict__ g, const float* __restrict__ nrm,
    const unsigned* __restrict__ rs, const unsigned* __restrict__ csr_src,
    const float* __restrict__ b, float* __restrict__ out, int n)
{
    __shared__ unsigned sidx[4][CAPG];
    __shared__ float    cf[4][CAPG];
    const int wid = threadIdx.x >> 6;
    const int lane = threadIdx.x & 63;
    const int i = blockIdx.x * 4 + wid;
    if (i >= n) return;
    const unsigned beg = rs[i];
    const int deg = (int)(rs[i + 1] - beg);
    const float ni = nrm[i];
    const int dcg = deg < CAPG ? deg : CAPG;
    for (int k = lane; k < dcg; k += 64) {
        unsigned s = csr_src[beg + k];
        sidx[wid][k] = s; cf[wid][k] = nrm[s];
    }
    __threadfence_block();
    const int half = lane >> 5, c = lane & 31;
    float acc = (half == 0) ? g[(size_t)i * 32 + c] * ni * ni : 0.f;
    auto edge = [&](int j, unsigned& s, float& w) {
        if (j < CAPG) { s = sidx[wid][j]; w = cf[wid][j] * ni; }
        else { s = csr_src[beg + j]; w = nrm[s] * ni; }
    };
    int j = half;
    for (; j + 2 < deg; j += 4) {          // this half handles j and j+2
        unsigned sa, sb; float wa, wb;
        edge(j, sa, wa); edge(j + 2, sb, wb);
        float va = g[(size_t)sa * 32 + c];
        float vb = g[(size_t)sb * 32 + c];
        acc = fmaf(va, wa, acc);
        acc = fmaf(vb, wb, acc);
    }
    for (; j < deg; j += 2) {
        unsigned s; float w; edge(j, s, w);
        acc = fmaf(g[(size_t)s * 32 + c], w, acc);
    }
    acc += __shfl_xor(acc, 32, 64);
    if (half == 0) out[(size_t)i * 32 + c] = fmaxf(acc + b[c], 0.f);
}

// ---------------- host ------------------------------------------------------
extern "C" void kernel_launch(void* const* d_in, const int* in_sizes, int n_in,
                              void* d_out, int out_size, void* d_ws, size_t ws_size,
                              hipStream_t stream)
{
    const float* x        = (const float*)d_in[0];
    const int*   eidx     = (const int*)d_in[1];
    const float* gat_W1   = (const float*)d_in[2];
    const float* att_s1   = (const float*)d_in[3];
    const float* att_d1   = (const float*)d_in[4];
    const float* gat_b1   = (const float*)d_in[5];
    const float* gat_W2   = (const float*)d_in[6];
    const float* att_s2   = (const float*)d_in[7];
    const float* att_d2   = (const float*)d_in[8];
    const float* gat_b2   = (const float*)d_in[9];
    const float* gcn_W1   = (const float*)d_in[10];
    const float* gcn_b1   = (const float*)d_in[11];
    const float* gcn_W2   = (const float*)d_in[12];
    const float* gcn_b2   = (const float*)d_in[13];
    const float* lin_W    = (const float*)d_in[14];
    const float* lin_b    = (const float*)d_in[15];
    const float* wc_p     = (const float*)d_in[16];
    const float* wt_p     = (const float*)d_in[17];

    const int n = in_sizes[0] / F_IN;      // 50000
    const int e = in_sizes[1] / 2;         // 800000
    const int* src = eidx;
    const int* dst = eidx + e;

    char* p = (char*)d_ws;
    auto alloc = [&](size_t bytes) -> void* {
        void* r = (void*)p;
        p += (bytes + 255) & ~(size_t)255;
        return r;
    };
    unsigned* counts  = (unsigned*)alloc((size_t)n * 4);
    unsigned* rs      = (unsigned*)alloc((size_t)(n + 1) * 4);
    unsigned* cursor  = (unsigned*)alloc((size_t)n * 4);
    unsigned* csr_src = (unsigned*)alloc((size_t)e * 4);
    float* nrm     = (float*)alloc((size_t)n * 4);
    float* as1     = (float*)alloc((size_t)n * 4 * 4);
    float* ad1     = (float*)alloc((size_t)n * 4 * 4);
    float* as2     = (float*)alloc((size_t)n * 4);
    float* ad2     = (float*)alloc((size_t)n * 4);
    float* cat     = (float*)alloc((size_t)n * 80 * 4);   // [gcn*wc | gat*wt]
    float* hg      = (float*)alloc((size_t)n * 80 * 4);   // [gat h2 | gcn g2]
    float* h1      = (float*)alloc((size_t)n * F_IN * 4); // GAT h1 | GCN g1/gacc1
    float* xg      = (float*)alloc((size_t)n * F_IN * 4); // GAT1 out (post-ELU)
    float* g1    = h1;                  // n*32
    float* gacc1 = h1 + (size_t)n * 32; // n*32

    const int EB = (e + 255) / 256;
    const int NB = (n + 255) / 256;
    const int WB = (n + 3) / 4;        // one wave per node, 4 waves/block

    // ---- CSR build ----
    hipMemsetAsync(counts, 0, (size_t)n * 4, stream);
    count_kernel<<<EB, 256, 0, stream>>>(dst, counts, e);
    scan_kernel<<<1, 1024, 0, stream>>>(counts, rs, cursor, n);
    fill_kernel<<<EB, 256, 0, stream>>>(src, dst, cursor, csr_src, e);
    norm_kernel<<<NB, 256, 0, stream>>>(rs, nrm, n);

    // ---- GCN branch (layer 1 + layer-2 GEMM into hg's gcn half) ----
    gemm_tile<128, 32, 128, 32><<<(n + 127) / 128, 256, 0, stream>>>(x, gcn_W1, nullptr, g1, n);
    gcn_agg1_kernel<<<WB, 256, 0, stream>>>(g1, nrm, rs, csr_src, gcn_b1, gacc1, n);
    gemm_tile<32, 40, 128, 32, 80><<<(n + 127) / 128, 320, 0, stream>>>(gacc1, gcn_W2, nullptr, hg + 40, n);

    // ---- GAT branch ----
    gemm_tile<128, 128, 64, 32><<<(n + 63) / 64, 512, 0, stream>>>(x, gat_W1, nullptr, h1, n);
    logits1_kernel<<<(n * 4 + 255) / 256, 256, 0, stream>>>(h1, att_s1, att_d1, as1, ad1, n);
    gat_agg1_kernel<<<WB, 256, 0, stream>>>(h1, as1, ad1, rs, csr_src, gat_b1, xg, n);
    gemm_tile<128, 40, 128, 32, 80><<<(n + 127) / 128, 320, 0, stream>>>(xg, gat_W2, nullptr, hg, n);
    logits2_kernel<<<NB, 256, 0, stream>>>(hg, att_s2, att_d2, as2, ad2, n);

    // ---- fused layer-2 aggregation (GAT + GCN) -> cat ----
    agg2_fused_kernel<<<WB, 256, 0, stream>>>(hg, as2, ad2, nrm, rs, csr_src,
                                              gat_b2, gcn_b2, wc_p, wt_p, cat, n);

    // ---- head: out = cat @ lin_W + lin_b ----
    gemm_tile<80, 40, 128, 40><<<(n + 127) / 128, 320, 0, stream>>>(cat, lin_W, lin_b, (float*)d_out, n);
}

// Round 4
// 447.629 us; speedup vs baseline: 2.4471x; 1.2293x over previous
//
#include <hip/hip_runtime.h>
#include <math.h>

#define F_IN   128
#define HIDC   32
#define NHEAD  4
#define CDIM   40
#define NEG_SLOPE 0.2f

__device__ __forceinline__ float leakyf(float x) { return x > 0.f ? x : NEG_SLOPE * x; }

__device__ __forceinline__ float wred_max(float v) {
#pragma unroll
    for (int o = 32; o > 0; o >>= 1) v = fmaxf(v, __shfl_xor(v, o, 64));
    return v;
}
__device__ __forceinline__ float wred_sum(float v) {
#pragma unroll
    for (int o = 32; o > 0; o >>= 1) v += __shfl_xor(v, o, 64);
    return v;
}
__device__ __forceinline__ float sel4(float4 v, int h) {
    return (h == 0) ? v.x : (h == 1) ? v.y : (h == 2) ? v.z : v.w;
}

// ---------------- tiled GEMM: Y[n,OUTC] = X[n,K] @ W[K,OUTC] (+bias) --------
template<int K, int OUTC, int BN, int BK, int OSTRIDE = OUTC>
__global__ __launch_bounds__((OUTC / 4) * (BN / 4)) void gemm_tile(
    const float* __restrict__ X, const float* __restrict__ W,
    const float* __restrict__ bias, float* __restrict__ Y, int n)
{
    constexpr int CG = OUTC / 4;
    constexpr int NG = BN / 4;
    constexpr int NT = CG * NG;
    __shared__ float Xs[BK][BN + 4];
    __shared__ float Ws[BK][OUTC];
    const int tid = threadIdx.x;
    const int cg = tid % CG, ng = tid / CG;
    const int node0 = blockIdx.x * BN;
    float acc[4][4] = {};

    for (int kb = 0; kb < K; kb += BK) {
        for (int idx = tid; idx < BN * (BK / 4); idx += NT) {
            int nd = idx / (BK / 4);
            int kq = idx % (BK / 4);
            int gnode = node0 + nd;
            float4 v = (gnode < n) ? *(const float4*)&X[(size_t)gnode * K + kb + kq * 4]
                                   : make_float4(0.f, 0.f, 0.f, 0.f);
            Xs[kq * 4 + 0][nd] = v.x;
            Xs[kq * 4 + 1][nd] = v.y;
            Xs[kq * 4 + 2][nd] = v.z;
            Xs[kq * 4 + 3][nd] = v.w;
        }
        for (int idx = tid; idx < BK * CG; idx += NT) {
            int kk = idx / CG;
            int cq = idx % CG;
            *(float4*)&Ws[kk][cq * 4] = *(const float4*)&W[(size_t)(kb + kk) * OUTC + cq * 4];
        }
        __syncthreads();
#pragma unroll
        for (int k = 0; k < BK; ++k) {
            float4 xv = *(const float4*)&Xs[k][ng * 4];
            float4 wv = *(const float4*)&Ws[k][cg * 4];
            float xa[4] = {xv.x, xv.y, xv.z, xv.w};
            float wa[4] = {wv.x, wv.y, wv.z, wv.w};
#pragma unroll
            for (int j = 0; j < 4; ++j)
#pragma unroll
                for (int c = 0; c < 4; ++c)
                    acc[j][c] = fmaf(xa[j], wa[c], acc[j][c]);
        }
        __syncthreads();
    }

    float4 bv = make_float4(0.f, 0.f, 0.f, 0.f);
    if (bias) bv = *(const float4*)&bias[cg * 4];
#pragma unroll
    for (int j = 0; j < 4; ++j) {
        int gnode = node0 + ng * 4 + j;
        if (gnode < n) {
            float4 o = make_float4(acc[j][0] + bv.x, acc[j][1] + bv.y,
                                   acc[j][2] + bv.z, acc[j][3] + bv.w);
            *(float4*)&Y[(size_t)gnode * OSTRIDE + cg * 4] = o;
        }
    }
}

// ---------------- CSR build -------------------------------------------------
__global__ void count_kernel(const int* __restrict__ dst, unsigned* __restrict__ counts, int e)
{
    int i = blockIdx.x * 256 + threadIdx.x;
    if (i < e) atomicAdd(&counts[dst[i]], 1u);
}

// stage 1: per-block (256 elems) reduce
__global__ __launch_bounds__(256) void scan_reduce_kernel(const unsigned* __restrict__ counts,
                                                          unsigned* __restrict__ partials, int n)
{
    __shared__ unsigned sm[256];
    int t = threadIdx.x;
    int i = blockIdx.x * 256 + t;
    unsigned v = (i < n) ? counts[i] : 0u;
    sm[t] = v;
    __syncthreads();
#pragma unroll
    for (int off = 128; off > 0; off >>= 1) {
        if (t < off) sm[t] += sm[t + off];
        __syncthreads();
    }
    if (t == 0) partials[blockIdx.x] = sm[0];
}

// stage 2: single block scans the partials (nb <= 256), writes exclusive offsets
__global__ __launch_bounds__(256) void scan_partials_kernel(unsigned* __restrict__ partials,
                                                            unsigned* __restrict__ rs, int nb, int n)
{
    __shared__ unsigned sm[256];
    int t = threadIdx.x;
    unsigned v = (t < nb) ? partials[t] : 0u;
    sm[t] = v;
    __syncthreads();
#pragma unroll
    for (int off = 1; off < 256; off <<= 1) {
        unsigned u = (t >= off) ? sm[t - off] : 0u;
        __syncthreads();
        sm[t] += u;
        __syncthreads();
    }
    if (t < nb) partials[t] = sm[t] - v;       // exclusive
    if (t == 255) rs[n] = sm[255];             // total = e
}

// stage 3: per-block exclusive scan + offset -> rs, cursor, nrm
__global__ __launch_bounds__(256) void scan_write_kernel(const unsigned* __restrict__ counts,
                                                         const unsigned* __restrict__ partials,
                                                         unsigned* __restrict__ rs,
                                                         unsigned* __restrict__ cursor,
                                                         float* __restrict__ nrm, int n)
{
    __shared__ unsigned sm[256];
    int t = threadIdx.x;
    int i = blockIdx.x * 256 + t;
    unsigned c = (i < n) ? counts[i] : 0u;
    sm[t] = c;
    __syncthreads();
#pragma unroll
    for (int off = 1; off < 256; off <<= 1) {
        unsigned u = (t >= off) ? sm[t - off] : 0u;
        __syncthreads();
        sm[t] += u;
        __syncthreads();
    }
    if (i < n) {
        unsigned val = partials[blockIdx.x] + sm[t] - c;   // exclusive
        rs[i] = val;
        cursor[i] = val;
        nrm[i] = rsqrtf((float)(c + 1u));                  // deg + self loop
    }
}

__global__ void fill_kernel(const int* __restrict__ src, const int* __restrict__ dst,
                            unsigned* __restrict__ cursor, unsigned* __restrict__ csr_src, int e)
{
    int i = blockIdx.x * 256 + threadIdx.x;
    if (i >= e) return;
    int d = dst[i];
    unsigned pos = atomicAdd(&cursor[d], 1u);
    csr_src[pos] = (unsigned)src[i];
}

// ---------------- attention logits -----------------------------------------
__global__ void logits1_kernel(const float* __restrict__ h1, const float* __restrict__ aw_s,
                               const float* __restrict__ aw_d, float* __restrict__ as1,
                               float* __restrict__ ad1, int n)
{
    __shared__ float sw[128], dw[128];
    if (threadIdx.x < 128) { sw[threadIdx.x] = aw_s[threadIdx.x]; dw[threadIdx.x] = aw_d[threadIdx.x]; }
    __syncthreads();
    int idx = blockIdx.x * 256 + threadIdx.x;
    if (idx >= n * NHEAD) return;
    int node = idx >> 2, h = idx & 3;
    const float* row = h1 + (size_t)node * F_IN + h * HIDC;
    float s = 0.f, d = 0.f;
#pragma unroll
    for (int k = 0; k < HIDC; ++k) {
        float v = row[k];
        s = fmaf(v, sw[h * HIDC + k], s);
        d = fmaf(v, dw[h * HIDC + k], d);
    }
    as1[idx] = s; ad1[idx] = d;
}

// h2 lives in the interleaved hg buffer: row stride 80, gat half at offset 0
__global__ void logits2_kernel(const float* __restrict__ hg, const float* __restrict__ aw_s,
                               const float* __restrict__ aw_d, float* __restrict__ as2,
                               float* __restrict__ ad2, int n)
{
    __shared__ float sw[CDIM], dw[CDIM];
    if (threadIdx.x < CDIM) { sw[threadIdx.x] = aw_s[threadIdx.x]; dw[threadIdx.x] = aw_d[threadIdx.x]; }
    __syncthreads();
    int i = blockIdx.x * 256 + threadIdx.x;
    if (i >= n) return;
    const float* row = hg + (size_t)i * 80;
    float s = 0.f, d = 0.f;
#pragma unroll
    for (int k = 0; k < CDIM; ++k) {
        float v = row[k];
        s = fmaf(v, sw[k], s);
        d = fmaf(v, dw[k], d);
    }
    as2[i] = s; ad2[i] = d;
}

// ---------------- GAT layer 1 aggregation ----------------------------------
#define CAP1 96
__global__ __launch_bounds__(256) void gat_agg1_kernel(
    const float* __restrict__ h1, const float* __restrict__ as1,
    const float* __restrict__ ad1, const unsigned* __restrict__ rs,
    const unsigned* __restrict__ csr_src, const float* __restrict__ b1,
    float* __restrict__ xg, int n)
{
    __shared__ unsigned sidx[4][CAP1];
    __shared__ float    w4[4][CAP1][4];
    const int wid = threadIdx.x >> 6;
    const int lane = threadIdx.x & 63;
    const int i = blockIdx.x * 4 + wid;
    if (i >= n) return;
    const unsigned beg = rs[i];
    const int deg = (int)(rs[i + 1] - beg);
    const float4* as1v = (const float4*)as1;
    float4 av = as1v[i];
    float4 dv = ((const float4*)ad1)[i];
    float4 es = make_float4(leakyf(av.x + dv.x), leakyf(av.y + dv.y),
                            leakyf(av.z + dv.z), leakyf(av.w + dv.w));
    float m0 = es.x, m1 = es.y, m2 = es.z, m3 = es.w;
    for (int k = lane; k < deg; k += 64) {
        unsigned s = csr_src[beg + k];
        float4 a = as1v[s];
        float e0 = leakyf(a.x + dv.x), e1 = leakyf(a.y + dv.y);
        float e2 = leakyf(a.z + dv.z), e3 = leakyf(a.w + dv.w);
        if (k < CAP1) {
            sidx[wid][k] = s;
            w4[wid][k][0] = e0; w4[wid][k][1] = e1;
            w4[wid][k][2] = e2; w4[wid][k][3] = e3;
        }
        m0 = fmaxf(m0, e0); m1 = fmaxf(m1, e1);
        m2 = fmaxf(m2, e2); m3 = fmaxf(m3, e3);
    }
    m0 = wred_max(m0); m1 = wred_max(m1); m2 = wred_max(m2); m3 = wred_max(m3);
    float s0 = 0.f, s1 = 0.f, s2 = 0.f, s3 = 0.f;
    if (lane == 0) {
        s0 = __expf(es.x - m0); s1 = __expf(es.y - m1);
        s2 = __expf(es.z - m2); s3 = __expf(es.w - m3);
    }
    const int dc = deg < CAP1 ? deg : CAP1;
    for (int k = lane; k < dc; k += 64) {
        float w0 = __expf(w4[wid][k][0] - m0); w4[wid][k][0] = w0; s0 += w0;
        float w1 = __expf(w4[wid][k][1] - m1); w4[wid][k][1] = w1; s1 += w1;
        float w2 = __expf(w4[wid][k][2] - m2); w4[wid][k][2] = w2; s2 += w2;
        float w3 = __expf(w4[wid][k][3] - m3); w4[wid][k][3] = w3; s3 += w3;
    }
    for (int k = CAP1 + lane; k < deg; k += 64) {
        unsigned s = csr_src[beg + k];
        float4 a = as1v[s];
        s0 += __expf(leakyf(a.x + dv.x) - m0);
        s1 += __expf(leakyf(a.y + dv.y) - m1);
        s2 += __expf(leakyf(a.z + dv.z) - m2);
        s3 += __expf(leakyf(a.w + dv.w) - m3);
    }
    s0 = wred_sum(s0); s1 = wred_sum(s1); s2 = wred_sum(s2); s3 = wred_sum(s3);
    __threadfence_block();
    const int h = lane >> 4;
    const float mh   = sel4(make_float4(m0, m1, m2, m3), h);
    const float advh = sel4(dv, h);
    const float ssh  = sel4(make_float4(s0, s1, s2, s3), h);
    const float wself = __expf(sel4(es, h) - mh);
    const float2* h1v = (const float2*)h1;
    float2 hv = h1v[(size_t)i * 64 + lane];
    float2 acc = make_float2(hv.x * wself, hv.y * wself);
    auto edge = [&](int j, unsigned& s, float& w) {
        if (j < CAP1) { s = sidx[wid][j]; w = w4[wid][j][h]; }
        else {
            s = csr_src[beg + j];
            float4 a = as1v[s];
            w = __expf(leakyf(sel4(a, h) + advh) - mh);
        }
    };
    int j = 0;
    for (; j + 4 <= deg; j += 4) {
        unsigned sa, sb, sc, sd; float wa, wb, wc, wd;
        edge(j, sa, wa); edge(j + 1, sb, wb); edge(j + 2, sc, wc); edge(j + 3, sd, wd);
        float2 va = h1v[(size_t)sa * 64 + lane];
        float2 vb = h1v[(size_t)sb * 64 + lane];
        float2 vc = h1v[(size_t)sc * 64 + lane];
        float2 vd = h1v[(size_t)sd * 64 + lane];
        acc.x = fmaf(va.x, wa, acc.x); acc.y = fmaf(va.y, wa, acc.y);
        acc.x = fmaf(vb.x, wb, acc.x); acc.y = fmaf(vb.y, wb, acc.y);
        acc.x = fmaf(vc.x, wc, acc.x); acc.y = fmaf(vc.y, wc, acc.y);
        acc.x = fmaf(vd.x, wd, acc.x); acc.y = fmaf(vd.y, wd, acc.y);
    }
    for (; j < deg; ++j) {
        unsigned s; float w; edge(j, s, w);
        float2 v = h1v[(size_t)s * 64 + lane];
        acc.x = fmaf(v.x, w, acc.x); acc.y = fmaf(v.y, w, acc.y);
    }
    float inv = 1.f / ssh;
    int c0 = 2 * lane;
    float o0 = acc.x * inv + b1[c0];
    float o1 = acc.y * inv + b1[c0 + 1];
    o0 = o0 > 0.f ? o0 : __expf(o0) - 1.f;   // ELU
    o1 = o1 > 0.f ? o1 : __expf(o1) - 1.f;
    xg[(size_t)i * F_IN + c0]     = o0;
    xg[(size_t)i * F_IN + c0 + 1] = o1;
}

// ---------------- fused layer-2 aggregation (GAT heads=1 + GCN), writes cat -
#define CAP2 128
__global__ __launch_bounds__(256) void agg2_fused_kernel(
    const float* __restrict__ hg, const float* __restrict__ as2,
    const float* __restrict__ ad2, const float* __restrict__ nrm,
    const unsigned* __restrict__ rs, const unsigned* __restrict__ csr_src,
    const float* __restrict__ gat_b2, const float* __restrict__ gcn_b2,
    const float* __restrict__ wc_p, const float* __restrict__ wt_p,
    float* __restrict__ cat, int n)
{
    __shared__ unsigned sidx[4][CAP2];
    __shared__ float    wgt[4][CAP2];
    __shared__ float    cf [4][CAP2];
    const int wid = threadIdx.x >> 6;
    const int lane = threadIdx.x & 63;
    const int i = blockIdx.x * 4 + wid;
    if (i >= n) return;
    const unsigned beg = rs[i];
    const int deg = (int)(rs[i + 1] - beg);
    const float adv = ad2[i];
    const float e_self = leakyf(as2[i] + adv);
    const float ni = nrm[i];
    float m = e_self;
    for (int k = lane; k < deg; k += 64) {
        unsigned s = csr_src[beg + k];
        float e = leakyf(as2[s] + adv);
        if (k < CAP2) { sidx[wid][k] = s; wgt[wid][k] = e; cf[wid][k] = nrm[s]; }
        m = fmaxf(m, e);
    }
    m = wred_max(m);
    float ssum = (lane == 0) ? __expf(e_self - m) : 0.f;
    const int dc = deg < CAP2 ? deg : CAP2;
    for (int k = lane; k < dc; k += 64) {
        float w = __expf(wgt[wid][k] - m);
        wgt[wid][k] = w; ssum += w;
    }
    for (int k = CAP2 + lane; k < deg; k += 64) {
        unsigned s = csr_src[beg + k];
        ssum += __expf(leakyf(as2[s] + adv) - m);
    }
    ssum = wred_sum(ssum);
    __threadfence_block();
    const bool act   = lane < 40;
    const bool isgat = lane < 20;
    const float selfw = isgat ? __expf(e_self - m) : ni * ni;
    const float2* rows = (const float2*)hg;
    float2 acc = make_float2(0.f, 0.f);
    if (act) {
        float2 v = rows[(size_t)i * 40 + lane];
        acc.x = v.x * selfw; acc.y = v.y * selfw;
    }
    auto edge = [&](int j, unsigned& s, float& w) {
        if (j < CAP2) {
            s = sidx[wid][j];
            w = isgat ? wgt[wid][j] : cf[wid][j] * ni;
        } else {
            s = csr_src[beg + j];
            w = isgat ? __expf(leakyf(as2[s] + adv) - m) : nrm[s] * ni;
        }
    };
    int j = 0;
    for (; j + 4 <= deg; j += 4) {
        unsigned sa, sb, sc, sd; float wa, wb, wc, wd;
        edge(j, sa, wa); edge(j + 1, sb, wb); edge(j + 2, sc, wc); edge(j + 3, sd, wd);
        if (act) {
            float2 va = rows[(size_t)sa * 40 + lane];
            float2 vb = rows[(size_t)sb * 40 + lane];
            float2 vc = rows[(size_t)sc * 40 + lane];
            float2 vd = rows[(size_t)sd * 40 + lane];
            acc.x = fmaf(va.x, wa, acc.x); acc.y = fmaf(va.y, wa, acc.y);
            acc.x = fmaf(vb.x, wb, acc.x); acc.y = fmaf(vb.y, wb, acc.y);
            acc.x = fmaf(vc.x, wc, acc.x); acc.y = fmaf(vc.y, wc, acc.y);
            acc.x = fmaf(vd.x, wd, acc.x); acc.y = fmaf(vd.y, wd, acc.y);
        }
    }
    for (; j < deg; ++j) {
        unsigned s; float w; edge(j, s, w);
        if (act) {
            float2 v = rows[(size_t)s * 40 + lane];
            acc.x = fmaf(v.x, w, acc.x); acc.y = fmaf(v.y, w, acc.y);
        }
    }
    if (act) {
        if (isgat) {
            float inv = 1.f / ssum, wt = *wt_p;
            int c0 = 2 * lane;
            cat[(size_t)i * 80 + 40 + c0]     = (acc.x * inv + gat_b2[c0]) * wt;
            cat[(size_t)i * 80 + 40 + c0 + 1] = (acc.y * inv + gat_b2[c0 + 1]) * wt;
        } else {
            float wc = *wc_p;
            int c0 = 2 * (lane - 20);
            cat[(size_t)i * 80 + c0]     = (acc.x + gcn_b2[c0]) * wc;
            cat[(size_t)i * 80 + c0 + 1] = (acc.y + gcn_b2[c0 + 1]) * wc;
        }
    }
}

// ---------------- GCN layer-1 aggregation (32 ch, two edges per iteration) --
#define CAPG 128
__global__ __launch_bounds__(256) void gcn_agg1_kernel(
    const float* __restrict__ g, const float* __restrict__ nrm,
    const unsigned* __restrict__ rs, const unsigned* __restrict__ csr_src,
    const float* __restrict__ b, float* __restrict__ out, int n)
{
    __shared__ unsigned sidx[4][CAPG];
    __shared__ float    cf[4][CAPG];
    const int wid = threadIdx.x >> 6;
    const int lane = threadIdx.x & 63;
    const int i = blockIdx.x * 4 + wid;
    if (i >= n) return;
    const unsigned beg = rs[i];
    const int deg = (int)(rs[i + 1] - beg);
    const float ni = nrm[i];
    const int dcg = deg < CAPG ? deg : CAPG;
    for (int k = lane; k < dcg; k += 64) {
        unsigned s = csr_src[beg + k];
        sidx[wid][k] = s; cf[wid][k] = nrm[s];
    }
    __threadfence_block();
    const int half = lane >> 5, c = lane & 31;
    float acc = (half == 0) ? g[(size_t)i * 32 + c] * ni * ni : 0.f;
    auto edge = [&](int j, unsigned& s, float& w) {
        if (j < CAPG) { s = sidx[wid][j]; w = cf[wid][j] * ni; }
        else { s = csr_src[beg + j]; w = nrm[s] * ni; }
    };
    int j = half;
    for (; j + 2 < deg; j += 4) {
        unsigned sa, sb; float wa, wb;
        edge(j, sa, wa); edge(j + 2, sb, wb);
        float va = g[(size_t)sa * 32 + c];
        float vb = g[(size_t)sb * 32 + c];
        acc = fmaf(va, wa, acc);
        acc = fmaf(vb, wb, acc);
    }
    for (; j < deg; j += 2) {
        unsigned s; float w; edge(j, s, w);
        acc = fmaf(g[(size_t)s * 32 + c], w, acc);
    }
    acc += __shfl_xor(acc, 32, 64);
    if (half == 0) out[(size_t)i * 32 + c] = fmaxf(acc + b[c], 0.f);
}

// ---------------- host ------------------------------------------------------
extern "C" void kernel_launch(void* const* d_in, const int* in_sizes, int n_in,
                              void* d_out, int out_size, void* d_ws, size_t ws_size,
                              hipStream_t stream)
{
    const float* x        = (const float*)d_in[0];
    const int*   eidx     = (const int*)d_in[1];
    const float* gat_W1   = (const float*)d_in[2];
    const float* att_s1   = (const float*)d_in[3];
    const float* att_d1   = (const float*)d_in[4];
    const float* gat_b1   = (const float*)d_in[5];
    const float* gat_W2   = (const float*)d_in[6];
    const float* att_s2   = (const float*)d_in[7];
    const float* att_d2   = (const float*)d_in[8];
    const float* gat_b2   = (const float*)d_in[9];
    const float* gcn_W1   = (const float*)d_in[10];
    const float* gcn_b1   = (const float*)d_in[11];
    const float* gcn_W2   = (const float*)d_in[12];
    const float* gcn_b2   = (const float*)d_in[13];
    const float* lin_W    = (const float*)d_in[14];
    const float* lin_b    = (const float*)d_in[15];
    const float* wc_p     = (const float*)d_in[16];
    const float* wt_p     = (const float*)d_in[17];

    const int n = in_sizes[0] / F_IN;      // 50000
    const int e = in_sizes[1] / 2;         // 800000
    const int* src = eidx;
    const int* dst = eidx + e;

    char* p = (char*)d_ws;
    auto alloc = [&](size_t bytes) -> void* {
        void* r = (void*)p;
        p += (bytes + 255) & ~(size_t)255;
        return r;
    };
    unsigned* counts  = (unsigned*)alloc((size_t)n * 4);
    unsigned* rs      = (unsigned*)alloc((size_t)(n + 1) * 4);
    unsigned* cursor  = (unsigned*)alloc((size_t)n * 4);
    unsigned* partials= (unsigned*)alloc(256 * 4);
    unsigned* csr_src = (unsigned*)alloc((size_t)e * 4);
    float* nrm     = (float*)alloc((size_t)n * 4);
    float* as1     = (float*)alloc((size_t)n * 4 * 4);
    float* ad1     = (float*)alloc((size_t)n * 4 * 4);
    float* as2     = (float*)alloc((size_t)n * 4);
    float* ad2     = (float*)alloc((size_t)n * 4);
    float* cat     = (float*)alloc((size_t)n * 80 * 4);   // [gcn*wc | gat*wt]
    float* hg      = (float*)alloc((size_t)n * 80 * 4);   // [gat h2 | gcn g2]
    float* h1      = (float*)alloc((size_t)n * F_IN * 4); // GAT h1 | GCN g1/gacc1
    float* xg      = (float*)alloc((size_t)n * F_IN * 4); // GAT1 out (post-ELU)
    float* g1    = h1;                  // n*32
    float* gacc1 = h1 + (size_t)n * 32; // n*32

    const int EB = (e + 255) / 256;
    const int NB = (n + 255) / 256;    // also the scan block count (196 <= 256)
    const int WB = (n + 3) / 4;        // one wave per node, 4 waves/block

    // ---- CSR build (parallel 3-stage scan) ----
    hipMemsetAsync(counts, 0, (size_t)n * 4, stream);
    count_kernel<<<EB, 256, 0, stream>>>(dst, counts, e);
    scan_reduce_kernel<<<NB, 256, 0, stream>>>(counts, partials, n);
    scan_partials_kernel<<<1, 256, 0, stream>>>(partials, rs, NB, n);
    scan_write_kernel<<<NB, 256, 0, stream>>>(counts, partials, rs, cursor, nrm, n);
    fill_kernel<<<EB, 256, 0, stream>>>(src, dst, cursor, csr_src, e);

    // ---- GCN branch (layer 1 + layer-2 GEMM into hg's gcn half) ----
    gemm_tile<128, 32, 128, 32><<<(n + 127) / 128, 256, 0, stream>>>(x, gcn_W1, nullptr, g1, n);
    gcn_agg1_kernel<<<WB, 256, 0, stream>>>(g1, nrm, rs, csr_src, gcn_b1, gacc1, n);
    gemm_tile<32, 40, 128, 32, 80><<<(n + 127) / 128, 320, 0, stream>>>(gacc1, gcn_W2, nullptr, hg + 40, n);

    // ---- GAT branch ----
    gemm_tile<128, 128, 64, 32><<<(n + 63) / 64, 512, 0, stream>>>(x, gat_W1, nullptr, h1, n);
    logits1_kernel<<<(n * 4 + 255) / 256, 256, 0, stream>>>(h1, att_s1, att_d1, as1, ad1, n);
    gat_agg1_kernel<<<WB, 256, 0, stream>>>(h1, as1, ad1, rs, csr_src, gat_b1, xg, n);
    gemm_tile<128, 40, 128, 32, 80><<<(n + 127) / 128, 320, 0, stream>>>(xg, gat_W2, nullptr, hg, n);
    logits2_kernel<<<NB, 256, 0, stream>>>(hg, att_s2, att_d2, as2, ad2, n);

    // ---- fused layer-2 aggregation (GAT + GCN) -> cat ----
    agg2_fused_kernel<<<WB, 256, 0, stream>>>(hg, as2, ad2, nrm, rs, csr_src,
                                              gat_b2, gcn_b2, wc_p, wt_p, cat, n);

    // ---- head: out = cat @ lin_W + lin_b ----
    gemm_tile<80, 40, 128, 40><<<(n + 127) / 128, 320, 0, stream>>>(cat, lin_W, lin_b, (float*)d_out, n);
}

// Round 5
// 435.534 us; speedup vs baseline: 2.5150x; 1.0278x over previous
//
#include <hip/hip_runtime.h>
#include <math.h>

#define F_IN   128
#define HIDC   32
#define NHEAD  4
#define CDIM   40
#define NEG_SLOPE 0.2f

__device__ __forceinline__ float leakyf(float x) { return x > 0.f ? x : NEG_SLOPE * x; }

__device__ __forceinline__ float wred_max(float v) {
#pragma unroll
    for (int o = 32; o > 0; o >>= 1) v = fmaxf(v, __shfl_xor(v, o, 64));
    return v;
}
__device__ __forceinline__ float wred_sum(float v) {
#pragma unroll
    for (int o = 32; o > 0; o >>= 1) v += __shfl_xor(v, o, 64);
    return v;
}
__device__ __forceinline__ float sel4(float4 v, int h) {
    return (h == 0) ? v.x : (h == 1) ? v.y : (h == 2) ? v.z : v.w;
}
// pack two floats to bf16x2 (RNE)
__device__ __forceinline__ unsigned pack2_bf16(float a, float b) {
    unsigned ua = __float_as_uint(a);
    unsigned ub = __float_as_uint(b);
    ua = (ua + 0x7FFFu + ((ua >> 16) & 1u)) >> 16;
    ub = (ub + 0x7FFFu + ((ub >> 16) & 1u)) >> 16;
    return ua | (ub << 16);
}
__device__ __forceinline__ float2 unpack2_bf16(unsigned p) {
    return make_float2(__uint_as_float(p << 16), __uint_as_float(p & 0xFFFF0000u));
}

// ---------------- fused first-layer GEMM: 160 cols = [gat 128 | gcn 32] -----
// h1 fp32 [n,128], h1b bf16 [n,128] (packed, 64 uints/row), g1b bf16 [n,32]
__global__ __launch_bounds__(640) void gemm1_fused_kernel(
    const float* __restrict__ X, const float* __restrict__ Wg,
    const float* __restrict__ Wc, float* __restrict__ h1,
    unsigned* __restrict__ h1b, unsigned* __restrict__ g1b, int n)
{
    constexpr int BN = 64, BK = 32, CG = 40, NT = 640;
    __shared__ float Xs[BK][BN + 4];
    __shared__ float Ws[BK][160];
    const int tid = threadIdx.x;
    const int cg = tid % CG, ng = tid / CG;
    const int node0 = blockIdx.x * BN;
    float acc[4][4] = {};

    for (int kb = 0; kb < 128; kb += BK) {
        for (int idx = tid; idx < BN * (BK / 4); idx += NT) {
            int nd = idx / (BK / 4);
            int kq = idx % (BK / 4);
            int gnode = node0 + nd;
            float4 v = (gnode < n) ? *(const float4*)&X[(size_t)gnode * 128 + kb + kq * 4]
                                   : make_float4(0.f, 0.f, 0.f, 0.f);
            Xs[kq * 4 + 0][nd] = v.x;
            Xs[kq * 4 + 1][nd] = v.y;
            Xs[kq * 4 + 2][nd] = v.z;
            Xs[kq * 4 + 3][nd] = v.w;
        }
        for (int idx = tid; idx < BK * CG; idx += NT) {
            int kk = idx / CG;
            int cq = idx % CG;
            float4 v = (cq < 32) ? *(const float4*)&Wg[(size_t)(kb + kk) * 128 + cq * 4]
                                 : *(const float4*)&Wc[(size_t)(kb + kk) * 32 + (cq - 32) * 4];
            *(float4*)&Ws[kk][cq * 4] = v;
        }
        __syncthreads();
#pragma unroll
        for (int k = 0; k < BK; ++k) {
            float4 xv = *(const float4*)&Xs[k][ng * 4];
            float4 wv = *(const float4*)&Ws[k][cg * 4];
            float xa[4] = {xv.x, xv.y, xv.z, xv.w};
            float wa[4] = {wv.x, wv.y, wv.z, wv.w};
#pragma unroll
            for (int j = 0; j < 4; ++j)
#pragma unroll
                for (int c = 0; c < 4; ++c)
                    acc[j][c] = fmaf(xa[j], wa[c], acc[j][c]);
        }
        __syncthreads();
    }
#pragma unroll
    for (int j = 0; j < 4; ++j) {
        int gnode = node0 + ng * 4 + j;
        if (gnode >= n) continue;
        uint2 pb = make_uint2(pack2_bf16(acc[j][0], acc[j][1]),
                              pack2_bf16(acc[j][2], acc[j][3]));
        if (cg < 32) {
            float4 o = make_float4(acc[j][0], acc[j][1], acc[j][2], acc[j][3]);
            *(float4*)&h1[(size_t)gnode * 128 + cg * 4] = o;
            *(uint2*)&h1b[(size_t)gnode * 64 + cg * 2] = pb;
        } else {
            *(uint2*)&g1b[(size_t)gnode * 16 + (cg - 32) * 2] = pb;
        }
    }
}

// ---------------- tiled GEMM: Y[n,OUTC] = X[n,K] @ W[K,OUTC] (+bias) --------
template<int K, int OUTC, int BN, int BK, int OSTRIDE = OUTC>
__global__ __launch_bounds__((OUTC / 4) * (BN / 4)) void gemm_tile(
    const float* __restrict__ X, const float* __restrict__ W,
    const float* __restrict__ bias, float* __restrict__ Y, int n)
{
    constexpr int CG = OUTC / 4;
    constexpr int NG = BN / 4;
    constexpr int NT = CG * NG;
    __shared__ float Xs[BK][BN + 4];
    __shared__ float Ws[BK][OUTC];
    const int tid = threadIdx.x;
    const int cg = tid % CG, ng = tid / CG;
    const int node0 = blockIdx.x * BN;
    float acc[4][4] = {};

    for (int kb = 0; kb < K; kb += BK) {
        for (int idx = tid; idx < BN * (BK / 4); idx += NT) {
            int nd = idx / (BK / 4);
            int kq = idx % (BK / 4);
            int gnode = node0 + nd;
            float4 v = (gnode < n) ? *(const float4*)&X[(size_t)gnode * K + kb + kq * 4]
                                   : make_float4(0.f, 0.f, 0.f, 0.f);
            Xs[kq * 4 + 0][nd] = v.x;
            Xs[kq * 4 + 1][nd] = v.y;
            Xs[kq * 4 + 2][nd] = v.z;
            Xs[kq * 4 + 3][nd] = v.w;
        }
        for (int idx = tid; idx < BK * CG; idx += NT) {
            int kk = idx / CG;
            int cq = idx % CG;
            *(float4*)&Ws[kk][cq * 4] = *(const float4*)&W[(size_t)(kb + kk) * OUTC + cq * 4];
        }
        __syncthreads();
#pragma unroll
        for (int k = 0; k < BK; ++k) {
            float4 xv = *(const float4*)&Xs[k][ng * 4];
            float4 wv = *(const float4*)&Ws[k][cg * 4];
            float xa[4] = {xv.x, xv.y, xv.z, xv.w};
            float wa[4] = {wv.x, wv.y, wv.z, wv.w};
#pragma unroll
            for (int j = 0; j < 4; ++j)
#pragma unroll
                for (int c = 0; c < 4; ++c)
                    acc[j][c] = fmaf(xa[j], wa[c], acc[j][c]);
        }
        __syncthreads();
    }

    float4 bv = make_float4(0.f, 0.f, 0.f, 0.f);
    if (bias) bv = *(const float4*)&bias[cg * 4];
#pragma unroll
    for (int j = 0; j < 4; ++j) {
        int gnode = node0 + ng * 4 + j;
        if (gnode < n) {
            float4 o = make_float4(acc[j][0] + bv.x, acc[j][1] + bv.y,
                                   acc[j][2] + bv.z, acc[j][3] + bv.w);
            *(float4*)&Y[(size_t)gnode * OSTRIDE + cg * 4] = o;
        }
    }
}

// ---------------- CSR build -------------------------------------------------
__global__ void count_kernel(const int* __restrict__ dst, unsigned* __restrict__ counts, int e)
{
    int i = blockIdx.x * 256 + threadIdx.x;
    if (i < e) atomicAdd(&counts[dst[i]], 1u);
}

__global__ __launch_bounds__(256) void scan_reduce_kernel(const unsigned* __restrict__ counts,
                                                          unsigned* __restrict__ partials, int n)
{
    __shared__ unsigned sm[256];
    int t = threadIdx.x;
    int i = blockIdx.x * 256 + t;
    unsigned v = (i < n) ? counts[i] : 0u;
    sm[t] = v;
    __syncthreads();
#pragma unroll
    for (int off = 128; off > 0; off >>= 1) {
        if (t < off) sm[t] += sm[t + off];
        __syncthreads();
    }
    if (t == 0) partials[blockIdx.x] = sm[0];
}

__global__ __launch_bounds__(256) void scan_partials_kernel(unsigned* __restrict__ partials,
                                                            unsigned* __restrict__ rs, int nb, int n)
{
    __shared__ unsigned sm[256];
    int t = threadIdx.x;
    unsigned v = (t < nb) ? partials[t] : 0u;
    sm[t] = v;
    __syncthreads();
#pragma unroll
    for (int off = 1; off < 256; off <<= 1) {
        unsigned u = (t >= off) ? sm[t - off] : 0u;
        __syncthreads();
        sm[t] += u;
        __syncthreads();
    }
    if (t < nb) partials[t] = sm[t] - v;       // exclusive
    if (t == 255) rs[n] = sm[255];             // total = e
}

__global__ __launch_bounds__(256) void scan_write_kernel(const unsigned* __restrict__ counts,
                                                         const unsigned* __restrict__ partials,
                                                         unsigned* __restrict__ rs,
                                                         unsigned* __restrict__ cursor,
                                                         float* __restrict__ nrm, int n)
{
    __shared__ unsigned sm[256];
    int t = threadIdx.x;
    int i = blockIdx.x * 256 + t;
    unsigned c = (i < n) ? counts[i] : 0u;
    sm[t] = c;
    __syncthreads();
#pragma unroll
    for (int off = 1; off < 256; off <<= 1) {
        unsigned u = (t >= off) ? sm[t - off] : 0u;
        __syncthreads();
        sm[t] += u;
        __syncthreads();
    }
    if (i < n) {
        unsigned val = partials[blockIdx.x] + sm[t] - c;   // exclusive
        rs[i] = val;
        cursor[i] = val;
        nrm[i] = rsqrtf((float)(c + 1u));                  // deg + self loop
    }
}

__global__ void fill_kernel(const int* __restrict__ src, const int* __restrict__ dst,
                            unsigned* __restrict__ cursor, unsigned* __restrict__ csr_src, int e)
{
    int i = blockIdx.x * 256 + threadIdx.x;
    if (i >= e) return;
    int d = dst[i];
    unsigned pos = atomicAdd(&cursor[d], 1u);
    csr_src[pos] = (unsigned)src[i];
}

// ---------------- attention logits -----------------------------------------
__global__ void logits1_kernel(const float* __restrict__ h1, const float* __restrict__ aw_s,
                               const float* __restrict__ aw_d, float* __restrict__ as1,
                               float* __restrict__ ad1, int n)
{
    __shared__ float sw[128], dw[128];
    if (threadIdx.x < 128) { sw[threadIdx.x] = aw_s[threadIdx.x]; dw[threadIdx.x] = aw_d[threadIdx.x]; }
    __syncthreads();
    int idx = blockIdx.x * 256 + threadIdx.x;
    if (idx >= n * NHEAD) return;
    int node = idx >> 2, h = idx & 3;
    const float* row = h1 + (size_t)node * F_IN + h * HIDC;
    float s = 0.f, d = 0.f;
#pragma unroll
    for (int k = 0; k < HIDC; ++k) {
        float v = row[k];
        s = fmaf(v, sw[h * HIDC + k], s);
        d = fmaf(v, dw[h * HIDC + k], d);
    }
    as1[idx] = s; ad1[idx] = d;
}

// h2 lives in the interleaved hg buffer: row stride 80, gat half at offset 0
__global__ void logits2_kernel(const float* __restrict__ hg, const float* __restrict__ aw_s,
                               const float* __restrict__ aw_d, float* __restrict__ as2,
                               float* __restrict__ ad2, int n)
{
    __shared__ float sw[CDIM], dw[CDIM];
    if (threadIdx.x < CDIM) { sw[threadIdx.x] = aw_s[threadIdx.x]; dw[threadIdx.x] = aw_d[threadIdx.x]; }
    __syncthreads();
    int i = blockIdx.x * 256 + threadIdx.x;
    if (i >= n) return;
    const float* row = hg + (size_t)i * 80;
    float s = 0.f, d = 0.f;
#pragma unroll
    for (int k = 0; k < CDIM; ++k) {
        float v = row[k];
        s = fmaf(v, sw[k], s);
        d = fmaf(v, dw[k], d);
    }
    as2[i] = s; ad2[i] = d;
}

// ---------------- GAT layer 1 aggregation (bf16 gather) ---------------------
#define CAP1 96
__global__ __launch_bounds__(256) void gat_agg1_kernel(
    const float* __restrict__ h1, const unsigned* __restrict__ h1b,
    const float* __restrict__ as1, const float* __restrict__ ad1,
    const unsigned* __restrict__ rs, const unsigned* __restrict__ csr_src,
    const float* __restrict__ b1, float* __restrict__ xg, int n)
{
    __shared__ unsigned sidx[4][CAP1];
    __shared__ float    w4[4][CAP1][4];
    const int wid = threadIdx.x >> 6;
    const int lane = threadIdx.x & 63;
    const int i = blockIdx.x * 4 + wid;
    if (i >= n) return;
    const unsigned beg = rs[i];
    const int deg = (int)(rs[i + 1] - beg);
    const float4* as1v = (const float4*)as1;
    float4 av = as1v[i];
    float4 dv = ((const float4*)ad1)[i];
    float4 es = make_float4(leakyf(av.x + dv.x), leakyf(av.y + dv.y),
                            leakyf(av.z + dv.z), leakyf(av.w + dv.w));
    float m0 = es.x, m1 = es.y, m2 = es.z, m3 = es.w;
    for (int k = lane; k < deg; k += 64) {
        unsigned s = csr_src[beg + k];
        float4 a = as1v[s];
        float e0 = leakyf(a.x + dv.x), e1 = leakyf(a.y + dv.y);
        float e2 = leakyf(a.z + dv.z), e3 = leakyf(a.w + dv.w);
        if (k < CAP1) {
            sidx[wid][k] = s;
            w4[wid][k][0] = e0; w4[wid][k][1] = e1;
            w4[wid][k][2] = e2; w4[wid][k][3] = e3;
        }
        m0 = fmaxf(m0, e0); m1 = fmaxf(m1, e1);
        m2 = fmaxf(m2, e2); m3 = fmaxf(m3, e3);
    }
    m0 = wred_max(m0); m1 = wred_max(m1); m2 = wred_max(m2); m3 = wred_max(m3);
    float s0 = 0.f, s1 = 0.f, s2 = 0.f, s3 = 0.f;
    if (lane == 0) {
        s0 = __expf(es.x - m0); s1 = __expf(es.y - m1);
        s2 = __expf(es.z - m2); s3 = __expf(es.w - m3);
    }
    const int dc = deg < CAP1 ? deg : CAP1;
    for (int k = lane; k < dc; k += 64) {
        float w0 = __expf(w4[wid][k][0] - m0); w4[wid][k][0] = w0; s0 += w0;
        float w1 = __expf(w4[wid][k][1] - m1); w4[wid][k][1] = w1; s1 += w1;
        float w2 = __expf(w4[wid][k][2] - m2); w4[wid][k][2] = w2; s2 += w2;
        float w3 = __expf(w4[wid][k][3] - m3); w4[wid][k][3] = w3; s3 += w3;
    }
    for (int k = CAP1 + lane; k < deg; k += 64) {
        unsigned s = csr_src[beg + k];
        float4 a = as1v[s];
        s0 += __expf(leakyf(a.x + dv.x) - m0);
        s1 += __expf(leakyf(a.y + dv.y) - m1);
        s2 += __expf(leakyf(a.z + dv.z) - m2);
        s3 += __expf(leakyf(a.w + dv.w) - m3);
    }
    s0 = wred_sum(s0); s1 = wred_sum(s1); s2 = wred_sum(s2); s3 = wred_sum(s3);
    __threadfence_block();
    const int h = lane >> 4;
    const float mh   = sel4(make_float4(m0, m1, m2, m3), h);
    const float advh = sel4(dv, h);
    const float ssh  = sel4(make_float4(s0, s1, s2, s3), h);
    const float wself = __expf(sel4(es, h) - mh);
    const float2* h1v = (const float2*)h1;
    float2 hv = h1v[(size_t)i * 64 + lane];        // self row fp32
    float2 acc = make_float2(hv.x * wself, hv.y * wself);
    auto edge = [&](int j, unsigned& s, float& w) {
        if (j < CAP1) { s = sidx[wid][j]; w = w4[wid][j][h]; }
        else {
            s = csr_src[beg + j];
            float4 a = as1v[s];
            w = __expf(leakyf(sel4(a, h) + advh) - mh);
        }
    };
    int j = 0;
    for (; j + 4 <= deg; j += 4) {
        unsigned sa, sb, sc, sd; float wa, wb, wc, wd;
        edge(j, sa, wa); edge(j + 1, sb, wb); edge(j + 2, sc, wc); edge(j + 3, sd, wd);
        float2 va = unpack2_bf16(h1b[(size_t)sa * 64 + lane]);
        float2 vb = unpack2_bf16(h1b[(size_t)sb * 64 + lane]);
        float2 vc = unpack2_bf16(h1b[(size_t)sc * 64 + lane]);
        float2 vd = unpack2_bf16(h1b[(size_t)sd * 64 + lane]);
        acc.x = fmaf(va.x, wa, acc.x); acc.y = fmaf(va.y, wa, acc.y);
        acc.x = fmaf(vb.x, wb, acc.x); acc.y = fmaf(vb.y, wb, acc.y);
        acc.x = fmaf(vc.x, wc, acc.x); acc.y = fmaf(vc.y, wc, acc.y);
        acc.x = fmaf(vd.x, wd, acc.x); acc.y = fmaf(vd.y, wd, acc.y);
    }
    for (; j < deg; ++j) {
        unsigned s; float w; edge(j, s, w);
        float2 v = unpack2_bf16(h1b[(size_t)s * 64 + lane]);
        acc.x = fmaf(v.x, w, acc.x); acc.y = fmaf(v.y, w, acc.y);
    }
    float inv = 1.f / ssh;
    int c0 = 2 * lane;
    float o0 = acc.x * inv + b1[c0];
    float o1 = acc.y * inv + b1[c0 + 1];
    o0 = o0 > 0.f ? o0 : __expf(o0) - 1.f;   // ELU
    o1 = o1 > 0.f ? o1 : __expf(o1) - 1.f;
    xg[(size_t)i * F_IN + c0]     = o0;
    xg[(size_t)i * F_IN + c0 + 1] = o1;
}

// ---------------- fused layer-2 aggregation (GAT heads=1 + GCN), writes cat -
#define CAP2 128
__global__ __launch_bounds__(256) void agg2_fused_kernel(
    const float* __restrict__ hg, const float* __restrict__ as2,
    const float* __restrict__ ad2, const float* __restrict__ nrm,
    const unsigned* __restrict__ rs, const unsigned* __restrict__ csr_src,
    const float* __restrict__ gat_b2, const float* __restrict__ gcn_b2,
    const float* __restrict__ wc_p, const float* __restrict__ wt_p,
    float* __restrict__ cat, int n)
{
    __shared__ unsigned sidx[4][CAP2];
    __shared__ float    wgt[4][CAP2];
    __shared__ float    cf [4][CAP2];
    const int wid = threadIdx.x >> 6;
    const int lane = threadIdx.x & 63;
    const int i = blockIdx.x * 4 + wid;
    if (i >= n) return;
    const unsigned beg = rs[i];
    const int deg = (int)(rs[i + 1] - beg);
    const float adv = ad2[i];
    const float e_self = leakyf(as2[i] + adv);
    const float ni = nrm[i];
    float m = e_self;
    for (int k = lane; k < deg; k += 64) {
        unsigned s = csr_src[beg + k];
        float e = leakyf(as2[s] + adv);
        if (k < CAP2) { sidx[wid][k] = s; wgt[wid][k] = e; cf[wid][k] = nrm[s]; }
        m = fmaxf(m, e);
    }
    m = wred_max(m);
    float ssum = (lane == 0) ? __expf(e_self - m) : 0.f;
    const int dc = deg < CAP2 ? deg : CAP2;
    for (int k = lane; k < dc; k += 64) {
        float w = __expf(wgt[wid][k] - m);
        wgt[wid][k] = w; ssum += w;
    }
    for (int k = CAP2 + lane; k < deg; k += 64) {
        unsigned s = csr_src[beg + k];
        ssum += __expf(leakyf(as2[s] + adv) - m);
    }
    ssum = wred_sum(ssum);
    __threadfence_block();
    const bool act   = lane < 40;
    const bool isgat = lane < 20;
    const float selfw = isgat ? __expf(e_self - m) : ni * ni;
    const float2* rows = (const float2*)hg;
    float2 acc = make_float2(0.f, 0.f);
    if (act) {
        float2 v = rows[(size_t)i * 40 + lane];
        acc.x = v.x * selfw; acc.y = v.y * selfw;
    }
    auto edge = [&](int j, unsigned& s, float& w) {
        if (j < CAP2) {
            s = sidx[wid][j];
            w = isgat ? wgt[wid][j] : cf[wid][j] * ni;
        } else {
            s = csr_src[beg + j];
            w = isgat ? __expf(leakyf(as2[s] + adv) - m) : nrm[s] * ni;
        }
    };
    int j = 0;
    for (; j + 4 <= deg; j += 4) {
        unsigned sa, sb, sc, sd; float wa, wb, wc, wd;
        edge(j, sa, wa); edge(j + 1, sb, wb); edge(j + 2, sc, wc); edge(j + 3, sd, wd);
        if (act) {
            float2 va = rows[(size_t)sa * 40 + lane];
            float2 vb = rows[(size_t)sb * 40 + lane];
            float2 vc = rows[(size_t)sc * 40 + lane];
            float2 vd = rows[(size_t)sd * 40 + lane];
            acc.x = fmaf(va.x, wa, acc.x); acc.y = fmaf(va.y, wa, acc.y);
            acc.x = fmaf(vb.x, wb, acc.x); acc.y = fmaf(vb.y, wb, acc.y);
            acc.x = fmaf(vc.x, wc, acc.x); acc.y = fmaf(vc.y, wc, acc.y);
            acc.x = fmaf(vd.x, wd, acc.x); acc.y = fmaf(vd.y, wd, acc.y);
        }
    }
    for (; j < deg; ++j) {
        unsigned s; float w; edge(j, s, w);
        if (act) {
            float2 v = rows[(size_t)s * 40 + lane];
            acc.x = fmaf(v.x, w, acc.x); acc.y = fmaf(v.y, w, acc.y);
        }
    }
    if (act) {
        if (isgat) {
            float inv = 1.f / ssum, wt = *wt_p;
            int c0 = 2 * lane;
            cat[(size_t)i * 80 + 40 + c0]     = (acc.x * inv + gat_b2[c0]) * wt;
            cat[(size_t)i * 80 + 40 + c0 + 1] = (acc.y * inv + gat_b2[c0 + 1]) * wt;
        } else {
            float wc = *wc_p;
            int c0 = 2 * (lane - 20);
            cat[(size_t)i * 80 + c0]     = (acc.x + gcn_b2[c0]) * wc;
            cat[(size_t)i * 80 + c0 + 1] = (acc.y + gcn_b2[c0 + 1]) * wc;
        }
    }
}

// ---------------- GCN layer-1 aggregation (bf16 gather, 3.2 MB table) -------
#define CAPG 128
__global__ __launch_bounds__(256) void gcn_agg1_kernel(
    const unsigned short* __restrict__ g1b, const float* __restrict__ nrm,
    const unsigned* __restrict__ rs, const unsigned* __restrict__ csr_src,
    const float* __restrict__ b, float* __restrict__ out, int n)
{
    __shared__ unsigned sidx[4][CAPG];
    __shared__ float    cf[4][CAPG];
    const int wid = threadIdx.x >> 6;
    const int lane = threadIdx.x & 63;
    const int i = blockIdx.x * 4 + wid;
    if (i >= n) return;
    const unsigned beg = rs[i];
    const int deg = (int)(rs[i + 1] - beg);
    const float ni = nrm[i];
    const int dcg = deg < CAPG ? deg : CAPG;
    for (int k = lane; k < dcg; k += 64) {
        unsigned s = csr_src[beg + k];
        sidx[wid][k] = s; cf[wid][k] = nrm[s];
    }
    __threadfence_block();
    const int half = lane >> 5, c = lane & 31;
    auto ldb = [&](unsigned node) {
        return __uint_as_float(((unsigned)g1b[(size_t)node * 32 + c]) << 16);
    };
    float acc = (half == 0) ? ldb(i) * ni * ni : 0.f;
    auto edge = [&](int j, unsigned& s, float& w) {
        if (j < CAPG) { s = sidx[wid][j]; w = cf[wid][j] * ni; }
        else { s = csr_src[beg + j]; w = nrm[s] * ni; }
    };
    int j = half;
    for (; j + 2 < deg; j += 4) {
        unsigned sa, sb; float wa, wb;
        edge(j, sa, wa); edge(j + 2, sb, wb);
        float va = ldb(sa);
        float vb = ldb(sb);
        acc = fmaf(va, wa, acc);
        acc = fmaf(vb, wb, acc);
    }
    for (; j < deg; j += 2) {
        unsigned s; float w; edge(j, s, w);
        acc = fmaf(ldb(s), w, acc);
    }
    acc += __shfl_xor(acc, 32, 64);
    if (half == 0) out[(size_t)i * 32 + c] = fmaxf(acc + b[c], 0.f);
}

// ---------------- host ------------------------------------------------------
extern "C" void kernel_launch(void* const* d_in, const int* in_sizes, int n_in,
                              void* d_out, int out_size, void* d_ws, size_t ws_size,
                              hipStream_t stream)
{
    const float* x        = (const float*)d_in[0];
    const int*   eidx     = (const int*)d_in[1];
    const float* gat_W1   = (const float*)d_in[2];
    const float* att_s1   = (const float*)d_in[3];
    const float* att_d1   = (const float*)d_in[4];
    const float* gat_b1   = (const float*)d_in[5];
    const float* gat_W2   = (const float*)d_in[6];
    const float* att_s2   = (const float*)d_in[7];
    const float* att_d2   = (const float*)d_in[8];
    const float* gat_b2   = (const float*)d_in[9];
    const float* gcn_W1   = (const float*)d_in[10];
    const float* gcn_b1   = (const float*)d_in[11];
    const float* gcn_W2   = (const float*)d_in[12];
    const float* gcn_b2   = (const float*)d_in[13];
    const float* lin_W    = (const float*)d_in[14];
    const float* lin_b    = (const float*)d_in[15];
    const float* wc_p     = (const float*)d_in[16];
    const float* wt_p     = (const float*)d_in[17];

    const int n = in_sizes[0] / F_IN;      // 50000
    const int e = in_sizes[1] / 2;         // 800000
    const int* src = eidx;
    const int* dst = eidx + e;

    char* p = (char*)d_ws;
    auto alloc = [&](size_t bytes) -> void* {
        void* r = (void*)p;
        p += (bytes + 255) & ~(size_t)255;
        return r;
    };
    unsigned* counts  = (unsigned*)alloc((size_t)n * 4);
    unsigned* rs      = (unsigned*)alloc((size_t)(n + 1) * 4);
    unsigned* cursor  = (unsigned*)alloc((size_t)n * 4);
    unsigned* partials= (unsigned*)alloc(256 * 4);
    unsigned* csr_src = (unsigned*)alloc((size_t)e * 4);
    float* nrm     = (float*)alloc((size_t)n * 4);
    float* as1     = (float*)alloc((size_t)n * 4 * 4);
    float* ad1     = (float*)alloc((size_t)n * 4 * 4);
    float* as2     = (float*)alloc((size_t)n * 4);
    float* ad2     = (float*)alloc((size_t)n * 4);
    float* cat     = (float*)alloc((size_t)n * 80 * 4);   // agg2 out; earlier: h1b
    float* hg      = (float*)alloc((size_t)n * 80 * 4);   // [gat h2 | gcn g2]
    float* h1      = (float*)alloc((size_t)n * F_IN * 4); // h1 fp32
    float* xg      = (float*)alloc((size_t)n * F_IN * 4); // GAT1 out; earlier: gacc1
    unsigned* g1b  = (unsigned*)alloc((size_t)n * 16 * 4);// g1 bf16 [n,32]
    // aliases with disjoint lifetimes (stream-ordered):
    unsigned* h1b  = (unsigned*)cat;    // h1 bf16 [n,128]: dead before cat written
    float*    gacc1 = xg;               // [n,32]: consumed before xg written

    const int EB = (e + 255) / 256;
    const int NB = (n + 255) / 256;
    const int WB = (n + 3) / 4;

    // ---- CSR build (parallel 3-stage scan) ----
    hipMemsetAsync(counts, 0, (size_t)n * 4, stream);
    count_kernel<<<EB, 256, 0, stream>>>(dst, counts, e);
    scan_reduce_kernel<<<NB, 256, 0, stream>>>(counts, partials, n);
    scan_partials_kernel<<<1, 256, 0, stream>>>(partials, rs, NB, n);
    scan_write_kernel<<<NB, 256, 0, stream>>>(counts, partials, rs, cursor, nrm, n);
    fill_kernel<<<EB, 256, 0, stream>>>(src, dst, cursor, csr_src, e);

    // ---- fused first-layer GEMM (GAT 128 + GCN 32 cols, one pass over x) ----
    gemm1_fused_kernel<<<(n + 63) / 64, 640, 0, stream>>>(x, gat_W1, gcn_W1, h1, h1b, g1b, n);

    // ---- GCN branch ----
    gcn_agg1_kernel<<<WB, 256, 0, stream>>>((const unsigned short*)g1b, nrm, rs, csr_src,
                                            gcn_b1, gacc1, n);
    gemm_tile<32, 40, 128, 32, 80><<<(n + 127) / 128, 320, 0, stream>>>(gacc1, gcn_W2, nullptr, hg + 40, n);

    // ---- GAT branch ----
    logits1_kernel<<<(n * 4 + 255) / 256, 256, 0, stream>>>(h1, att_s1, att_d1, as1, ad1, n);
    gat_agg1_kernel<<<WB, 256, 0, stream>>>(h1, h1b, as1, ad1, rs, csr_src, gat_b1, xg, n);
    gemm_tile<128, 40, 128, 32, 80><<<(n + 127) / 128, 320, 0, stream>>>(xg, gat_W2, nullptr, hg, n);
    logits2_kernel<<<NB, 256, 0, stream>>>(hg, att_s2, att_d2, as2, ad2, n);

    // ---- fused layer-2 aggregation (GAT + GCN) -> cat ----
    agg2_fused_kernel<<<WB, 256, 0, stream>>>(hg, as2, ad2, nrm, rs, csr_src,
                                              gat_b2, gcn_b2, wc_p, wt_p, cat, n);

    // ---- head: out = cat @ lin_W + lin_b ----
    gemm_tile<80, 40, 128, 40><<<(n + 127) / 128, 320, 0, stream>>>(cat, lin_W, lin_b, (float*)d_out, n);
}